// Round 1
// baseline (428.758 us; speedup 1.0000x reference)
//
#include <hip/hip_runtime.h>
#include <math.h>

#define SEQ   2048
#define DM    1024
#define LDQKV 3072
#define MTOK  4096   // B*T

typedef float  f32x4   __attribute__((ext_vector_type(4)));
typedef __bf16 bf16x8  __attribute__((ext_vector_type(8)));
typedef short  short8  __attribute__((ext_vector_type(8)));
typedef short  short4v __attribute__((ext_vector_type(4)));

__device__ __forceinline__ short f2bf(float f) {
  union { float f; unsigned u; } v; v.f = f;
  unsigned r = v.u + 0x7fffu + ((v.u >> 16) & 1u);
  return (short)(r >> 16);
}

__device__ __forceinline__ void gl_lds16(const void* g, void* l) {
  __builtin_amdgcn_global_load_lds(
      (const __attribute__((address_space(1))) void*)g,
      (__attribute__((address_space(3))) void*)l, 16, 0, 0);
}

__device__ __forceinline__ f32x4 mfma_bf16(bf16x8 a, bf16x8 b, f32x4 c) {
  return __builtin_amdgcn_mfma_f32_16x16x32_bf16(a, b, c, 0, 0, 0);
}

// ---------------------------------------------------------------------------
// Weight cast+transpose: W [K,N] fp32 -> Wt [N,K] bf16
// ---------------------------------------------------------------------------
__global__ __launch_bounds__(256) void transpose_cast_k(
    const float* __restrict__ W, short* __restrict__ Wt, int K, int N)
{
  __shared__ float tile[32][33];
  const int n0 = blockIdx.x * 32, k0 = blockIdx.y * 32;
  const int tx = threadIdx.x & 31, ty = threadIdx.x >> 5;   // 32 x 8
#pragma unroll
  for (int i = 0; i < 4; i++)
    tile[ty + i * 8][tx] = W[(size_t)(k0 + ty + i * 8) * N + n0 + tx];
  __syncthreads();
#pragma unroll
  for (int i = 0; i < 4; i++)
    Wt[(size_t)(n0 + ty + i * 8) * K + k0 + tx] = f2bf(tile[tx][ty + i * 8]);
}

// ---------------------------------------------------------------------------
// LayerNorm row kernel: x fp32 [rows,1024] -> out bf16
// ---------------------------------------------------------------------------
__global__ __launch_bounds__(256) void ln_k(
    const float* __restrict__ x, const float* __restrict__ g,
    const float* __restrict__ b, short* __restrict__ out)
{
  const int row = blockIdx.x;
  const int tid = threadIdx.x;
  const float4 v = ((const float4*)(x + (size_t)row * DM))[tid];
  float s  = v.x + v.y + v.z + v.w;
  float ss = v.x * v.x + v.y * v.y + v.z * v.z + v.w * v.w;
#pragma unroll
  for (int m = 32; m >= 1; m >>= 1) { s += __shfl_xor(s, m); ss += __shfl_xor(ss, m); }
  __shared__ float red[8];
  const int wid = tid >> 6;
  if ((tid & 63) == 0) { red[wid] = s; red[4 + wid] = ss; }
  __syncthreads();
  s  = red[0] + red[1] + red[2] + red[3];
  ss = red[4] + red[5] + red[6] + red[7];
  const float mu  = s * (1.f / DM);
  const float var = ss * (1.f / DM) - mu * mu;
  const float rs  = rsqrtf(var + 1e-5f);
  const float4 gv = ((const float4*)g)[tid];
  const float4 bv = ((const float4*)b)[tid];
  short4v o;
  o[0] = f2bf((v.x - mu) * rs * gv.x + bv.x);
  o[1] = f2bf((v.y - mu) * rs * gv.y + bv.y);
  o[2] = f2bf((v.z - mu) * rs * gv.z + bv.z);
  o[3] = f2bf((v.w - mu) * rs * gv.w + bv.w);
  *(short4v*)(out + (size_t)row * DM + tid * 4) = o;
}

__global__ __launch_bounds__(256) void concat_bias_k(
    const float* __restrict__ bq, const float* __restrict__ bk,
    const float* __restrict__ bv, float* __restrict__ o)
{
  int i = blockIdx.x * 256 + threadIdx.x;
  if (i < 3072) {
    float v = (i < 1024) ? bq[i] : (i < 2048 ? bk[i - 1024] : bv[i - 2048]);
    o[i] = v;
  }
}

// ---------------------------------------------------------------------------
// GEMM: C[M,N] = A[M,K](bf16) * Bt[N,K](bf16)^T + bias (+gelu) (+resid)
// 128x128 tile, BK=32, 4 waves (2x2 of 64x64), global_load_lds staging.
// ---------------------------------------------------------------------------
template <bool GELU_, bool RESID, bool OUTBF16>
__global__ __launch_bounds__(256) void gemm_bt(
    const short* __restrict__ A, const short* __restrict__ Bt,
    const float* __restrict__ bias, const float* __restrict__ resid,
    void* __restrict__ Cout, int M, int N, int K)
{
  __shared__ __align__(16) short Abuf[128 * 32];
  __shared__ __align__(16) short Bbuf[128 * 32];
  const int tid = threadIdx.x, lane = tid & 63, wid = tid >> 6;
  const int wr = wid >> 1, wc = wid & 1;
  const int bm = blockIdx.x * 128, bn = blockIdx.y * 128;

  f32x4 acc[4][4] = {};

  // staging addresses: each wave stages 32 rows of A and 32 rows of Bt
  const int arow  = wid * 32 + (lane >> 2);
  const int acol8 = (lane & 3) * 8;
  const short* Ag0 = A  + (size_t)(bm + arow)      * K + acol8;
  const short* Ag1 = A  + (size_t)(bm + arow + 16) * K + acol8;
  const short* Bg0 = Bt + (size_t)(bn + arow)      * K + acol8;
  const short* Bg1 = Bt + (size_t)(bn + arow + 16) * K + acol8;
  short* Al0 = &Abuf[(wid * 32) * 32];
  short* Al1 = &Abuf[(wid * 32 + 16) * 32];
  short* Bl0 = &Bbuf[(wid * 32) * 32];
  short* Bl1 = &Bbuf[(wid * 32 + 16) * 32];

  for (int k0 = 0; k0 < K; k0 += 32) {
    gl_lds16(Ag0 + k0, Al0);
    gl_lds16(Ag1 + k0, Al1);
    gl_lds16(Bg0 + k0, Bl0);
    gl_lds16(Bg1 + k0, Bl1);
    __syncthreads();
    bf16x8 a[4], b[4];
#pragma unroll
    for (int mi = 0; mi < 4; mi++)
      a[mi] = *(const bf16x8*)&Abuf[(wr * 64 + mi * 16 + (lane & 15)) * 32 + (lane >> 4) * 8];
#pragma unroll
    for (int ni = 0; ni < 4; ni++)
      b[ni] = *(const bf16x8*)&Bbuf[(wc * 64 + ni * 16 + (lane & 15)) * 32 + (lane >> 4) * 8];
#pragma unroll
    for (int mi = 0; mi < 4; mi++)
#pragma unroll
      for (int ni = 0; ni < 4; ni++)
        acc[mi][ni] = mfma_bf16(a[mi], b[ni], acc[mi][ni]);
    __syncthreads();
  }

#pragma unroll
  for (int mi = 0; mi < 4; mi++) {
#pragma unroll
    for (int ni = 0; ni < 4; ni++) {
      const int col = bn + wc * 64 + ni * 16 + (lane & 15);
      const float bs = bias[col];
#pragma unroll
      for (int j = 0; j < 4; j++) {
        const int row = bm + wr * 64 + mi * 16 + (lane >> 4) * 4 + j;
        float v = acc[mi][ni][j] + bs;
        if (GELU_) v = 0.5f * v * (1.0f + erff(v * 0.70710678118654752f));
        if (RESID) v += resid[(size_t)row * N + col];
        if (OUTBF16) ((short*)Cout)[(size_t)row * N + col] = f2bf(v);
        else         ((float*)Cout)[(size_t)row * N + col] = v;
      }
    }
  }
}

// ---------------------------------------------------------------------------
// Flash attention: 1 block per (b, h, 64 q-rows); 4 waves x 16 rows.
// K/V staged per 64-key tile in LDS (XOR-swizzled); online softmax; PV MFMA.
// Q/K/V live in a fused [4096, 3072] bf16 buffer (row stride LDQKV).
// ---------------------------------------------------------------------------
__global__ __launch_bounds__(256) void attn_k(
    const short* __restrict__ Qg, const short* __restrict__ Kg,
    const short* __restrict__ Vg, short* __restrict__ Og)
{
  const int b = blockIdx.z, h = blockIdx.y, q0 = blockIdx.x * 64;
  const int tid = threadIdx.x, lane = tid & 63, wid = tid >> 6;

  __shared__ __align__(16) short Klds[64 * 64];
  __shared__ __align__(16) short Vtld[64 * 64];
  __shared__ __align__(16) short Plds[4 * 16 * 64];

  char* KbC = (char*)Klds;
  char* VbC = (char*)Vtld;
  char* PbC = (char*)Plds + wid * 2048;   // per-wave 16x64 bf16

  const size_t qbase = (size_t)(b * SEQ + q0 + wid * 16 + (lane & 15)) * LDQKV + h * 64;
  const bf16x8 qf0 = *(const bf16x8*)&Qg[qbase + (lane >> 4) * 8];
  const bf16x8 qf1 = *(const bf16x8*)&Qg[qbase + 32 + (lane >> 4) * 8];

  float m_run[4] = { -1e30f, -1e30f, -1e30f, -1e30f };
  float l_run[4] = { 0.f, 0.f, 0.f, 0.f };
  f32x4 oacc[4] = {};

  for (int kt = 0; kt < SEQ; kt += 64) {
    // ---- stage K tile [64 keys][64 dims], swizzled rows of 128B
#pragma unroll
    for (int i = 0; i < 2; i++) {
      const int c = tid + i * 256;
      const int row = c >> 3, cc = c & 7;
      short8 kv = *(const short8*)&Kg[(size_t)(b * SEQ + kt + row) * LDQKV + h * 64 + cc * 8];
      *(short8*)(KbC + row * 128 + ((cc * 16) ^ ((row & 7) << 4))) = kv;
    }
    // ---- stage V transposed: Vt[dim][key], swizzled
#pragma unroll
    for (int i = 0; i < 2; i++) {
      const int c = tid + i * 256;
      const int key = c >> 3, dc = c & 7;
      short8 vv = *(const short8*)&Vg[(size_t)(b * SEQ + kt + key) * LDQKV + h * 64 + dc * 8];
#pragma unroll
      for (int d = 0; d < 8; d++)
        *(short*)(VbC + (dc * 8 + d) * 128 + ((key * 2) ^ (d << 4))) = vv[d];
    }
    __syncthreads();

    // ---- S = (Q K^T) * scale ; four 16-key sub-tiles
    f32x4 s[4];
#pragma unroll
    for (int kc = 0; kc < 4; kc++) {
      const int krow = kc * 16 + (lane & 15);
      const int sw = (krow & 7) << 4;
      bf16x8 kf0 = *(const bf16x8*)(KbC + krow * 128 + (((lane >> 4) * 16) ^ sw));
      bf16x8 kf1 = *(const bf16x8*)(KbC + krow * 128 + ((64 + (lane >> 4) * 16) ^ sw));
      f32x4 z = (f32x4){0.f, 0.f, 0.f, 0.f};
      z = mfma_bf16(qf0, kf0, z);
      z = mfma_bf16(qf1, kf1, z);
      s[kc] = z * 0.125f;
    }

    // ---- online softmax (rows distributed: row=(lane>>4)*4+j, key=lane&15)
#pragma unroll
    for (int j = 0; j < 4; j++) {
      float t = fmaxf(fmaxf(s[0][j], s[1][j]), fmaxf(s[2][j], s[3][j]));
      t = fmaxf(t, __shfl_xor(t, 1));
      t = fmaxf(t, __shfl_xor(t, 2));
      t = fmaxf(t, __shfl_xor(t, 4));
      t = fmaxf(t, __shfl_xor(t, 8));
      const float mnew = fmaxf(m_run[j], t);
      const float r = __expf(m_run[j] - mnew);
      m_run[j] = mnew;
      float rsum = 0.f;
      const int prow = (lane >> 4) * 4 + j;
      const int psw = (prow & 7) << 4;
#pragma unroll
      for (int kc = 0; kc < 4; kc++) {
        const float p = __expf(s[kc][j] - mnew);
        rsum += p;
        *(short*)(PbC + prow * 128 + (((kc * 16 + (lane & 15)) * 2) ^ psw)) = f2bf(p);
      }
      rsum += __shfl_xor(rsum, 1);
      rsum += __shfl_xor(rsum, 2);
      rsum += __shfl_xor(rsum, 4);
      rsum += __shfl_xor(rsum, 8);
      l_run[j] = l_run[j] * r + rsum;
#pragma unroll
      for (int vt = 0; vt < 4; vt++) oacc[vt][j] *= r;
    }

    // ---- PV: O += P[16x64] @ V[64x64]
#pragma unroll
    for (int c = 0; c < 2; c++) {
      const int prow = lane & 15;
      bf16x8 pf = *(const bf16x8*)(PbC + prow * 128 + ((c * 64 + (lane >> 4) * 16) ^ ((prow & 7) << 4)));
#pragma unroll
      for (int vt = 0; vt < 4; vt++) {
        const int vrow = vt * 16 + (lane & 15);
        bf16x8 vf = *(const bf16x8*)(VbC + vrow * 128 + ((c * 64 + (lane >> 4) * 16) ^ ((vrow & 7) << 4)));
        oacc[vt] = mfma_bf16(pf, vf, oacc[vt]);
      }
    }
    __syncthreads();
  }

  // ---- epilogue: normalize and store bf16 [4096,1024]
#pragma unroll
  for (int vt = 0; vt < 4; vt++) {
#pragma unroll
    for (int j = 0; j < 4; j++) {
      const int q = q0 + wid * 16 + (lane >> 4) * 4 + j;
      const float v = oacc[vt][j] / l_run[j];
      Og[(size_t)(b * SEQ + q) * DM + h * 64 + vt * 16 + (lane & 15)] = f2bf(v);
    }
  }
}

// ---------------------------------------------------------------------------
extern "C" void kernel_launch(void* const* d_in, const int* in_sizes, int n_in,
                              void* d_out, int out_size, void* d_ws, size_t ws_size,
                              hipStream_t stream)
{
  const float* x    = (const float*)d_in[0];
  const float* Wq   = (const float*)d_in[1];
  const float* bq   = (const float*)d_in[2];
  const float* Wk   = (const float*)d_in[3];
  const float* bk   = (const float*)d_in[4];
  const float* Wv   = (const float*)d_in[5];
  const float* bv   = (const float*)d_in[6];
  const float* Wo   = (const float*)d_in[7];
  const float* bo   = (const float*)d_in[8];
  const float* W1   = (const float*)d_in[9];
  const float* b1   = (const float*)d_in[10];
  const float* W2   = (const float*)d_in[11];
  const float* b2   = (const float*)d_in[12];
  const float* ln1g = (const float*)d_in[13];
  const float* ln1b = (const float*)d_in[14];
  const float* ln2g = (const float*)d_in[15];
  const float* ln2b = (const float*)d_in[16];

  char* ws = (char*)d_ws;
  const size_t MB = 1024 * 1024;
  short* Wqkvt = (short*)(ws + 0 * MB);           // [3072][1024] bf16 (Wq|Wk|Wv rows)
  short* Wqt   = Wqkvt;
  short* Wkt   = (short*)(ws + 2 * MB);
  short* Wvt   = (short*)(ws + 4 * MB);
  short* Wot   = (short*)(ws + 6 * MB);           // [1024][1024]
  short* W1t   = (short*)(ws + 8 * MB);           // [4096][1024]
  short* W2t   = (short*)(ws + 16 * MB);          // [1024][4096]
  short* hbuf  = (short*)(ws + 24 * MB);          // [4096][1024] bf16 (h, later h2)
  short* QKV   = (short*)(ws + 32 * MB);          // [4096][3072] bf16
  short* AO    = (short*)(ws + 56 * MB);          // [4096][1024] bf16
  float* x1    = (float*)(ws + 64 * MB);          // [4096][1024] fp32
  float* bqkv  = (float*)(ws + 80 * MB);          // [3072] fp32
  short* gbuf  = (short*)(ws + 32 * MB);          // [4096][4096] bf16, aliases QKV+AO

  dim3 tb(256);

  // weight cast+transpose (Wq|Wk|Wv contiguous -> fused QKV weight [3072][1024])
  transpose_cast_k<<<dim3(32, 32),  tb, 0, stream>>>(Wq, Wqt, 1024, 1024);
  transpose_cast_k<<<dim3(32, 32),  tb, 0, stream>>>(Wk, Wkt, 1024, 1024);
  transpose_cast_k<<<dim3(32, 32),  tb, 0, stream>>>(Wv, Wvt, 1024, 1024);
  transpose_cast_k<<<dim3(32, 32),  tb, 0, stream>>>(Wo, Wot, 1024, 1024);
  transpose_cast_k<<<dim3(128, 32), tb, 0, stream>>>(W1, W1t, 1024, 4096);
  transpose_cast_k<<<dim3(32, 128), tb, 0, stream>>>(W2, W2t, 4096, 1024);
  concat_bias_k<<<dim3(12), tb, 0, stream>>>(bq, bk, bv, bqkv);

  // LN1
  ln_k<<<dim3(MTOK), tb, 0, stream>>>(x, ln1g, ln1b, hbuf);

  // fused QKV projection: [4096,1024] x [3072,1024]^T -> [4096,3072] bf16
  gemm_bt<false, false, true><<<dim3(32, 24), tb, 0, stream>>>(
      hbuf, Wqkvt, bqkv, nullptr, QKV, MTOK, 3072, 1024);

  // attention
  attn_k<<<dim3(32, 16, 2), tb, 0, stream>>>(QKV, QKV + 1024, QKV + 2048, AO);

  // O-projection + residual: x1 = x + AO @ Wo + bo  (fp32 out)
  gemm_bt<false, true, false><<<dim3(32, 8), tb, 0, stream>>>(
      AO, Wot, bo, x, x1, MTOK, 1024, 1024);

  // LN2
  ln_k<<<dim3(MTOK), tb, 0, stream>>>(x1, ln2g, ln2b, hbuf);

  // FFN1 + GELU: [4096,1024] x [4096,1024]^T -> [4096,4096] bf16
  gemm_bt<true, false, true><<<dim3(32, 32), tb, 0, stream>>>(
      hbuf, W1t, b1, nullptr, gbuf, MTOK, 4096, 1024);

  // FFN2 + residual -> d_out fp32
  gemm_bt<false, true, false><<<dim3(32, 8), tb, 0, stream>>>(
      gbuf, W2t, b2, x1, (float*)d_out, MTOK, 1024, 4096);
}

// Round 2
// 366.838 us; speedup vs baseline: 1.1688x; 1.1688x over previous
//
#include <hip/hip_runtime.h>
#include <math.h>

#define SEQ   2048
#define DM    1024
#define LDQKV 3072
#define MTOK  4096   // B*T

typedef float  f32x4   __attribute__((ext_vector_type(4)));
typedef __bf16 bf16x8  __attribute__((ext_vector_type(8)));
typedef short  short8  __attribute__((ext_vector_type(8)));
typedef short  short4v __attribute__((ext_vector_type(4)));

__device__ __forceinline__ short f2bf(float f) {
  union { float f; unsigned u; } v; v.f = f;
  unsigned r = v.u + 0x7fffu + ((v.u >> 16) & 1u);
  return (short)(r >> 16);
}

__device__ __forceinline__ void gl_lds16(const void* g, void* l) {
  __builtin_amdgcn_global_load_lds(
      (const __attribute__((address_space(1))) void*)g,
      (__attribute__((address_space(3))) void*)l, 16, 0, 0);
}

__device__ __forceinline__ f32x4 mfma_bf16(bf16x8 a, bf16x8 b, f32x4 c) {
  return __builtin_amdgcn_mfma_f32_16x16x32_bf16(a, b, c, 0, 0, 0);
}

// ---------------------------------------------------------------------------
// Weight cast+transpose: W [K,N] fp32 -> Wt [N,K] bf16
// ---------------------------------------------------------------------------
__global__ __launch_bounds__(256) void transpose_cast_k(
    const float* __restrict__ W, short* __restrict__ Wt, int K, int N)
{
  __shared__ float tile[32][33];
  const int n0 = blockIdx.x * 32, k0 = blockIdx.y * 32;
  const int tx = threadIdx.x & 31, ty = threadIdx.x >> 5;   // 32 x 8
#pragma unroll
  for (int i = 0; i < 4; i++)
    tile[ty + i * 8][tx] = W[(size_t)(k0 + ty + i * 8) * N + n0 + tx];
  __syncthreads();
#pragma unroll
  for (int i = 0; i < 4; i++)
    Wt[(size_t)(n0 + ty + i * 8) * K + k0 + tx] = f2bf(tile[tx][ty + i * 8]);
}

// ---------------------------------------------------------------------------
// LayerNorm row kernel: x fp32 [rows,1024] -> out bf16
// ---------------------------------------------------------------------------
__global__ __launch_bounds__(256) void ln_k(
    const float* __restrict__ x, const float* __restrict__ g,
    const float* __restrict__ b, short* __restrict__ out)
{
  const int row = blockIdx.x;
  const int tid = threadIdx.x;
  const float4 v = ((const float4*)(x + (size_t)row * DM))[tid];
  float s  = v.x + v.y + v.z + v.w;
  float ss = v.x * v.x + v.y * v.y + v.z * v.z + v.w * v.w;
#pragma unroll
  for (int m = 32; m >= 1; m >>= 1) { s += __shfl_xor(s, m); ss += __shfl_xor(ss, m); }
  __shared__ float red[8];
  const int wid = tid >> 6;
  if ((tid & 63) == 0) { red[wid] = s; red[4 + wid] = ss; }
  __syncthreads();
  s  = red[0] + red[1] + red[2] + red[3];
  ss = red[4] + red[5] + red[6] + red[7];
  const float mu  = s * (1.f / DM);
  const float var = ss * (1.f / DM) - mu * mu;
  const float rs  = rsqrtf(var + 1e-5f);
  const float4 gv = ((const float4*)g)[tid];
  const float4 bv = ((const float4*)b)[tid];
  short4v o;
  o[0] = f2bf((v.x - mu) * rs * gv.x + bv.x);
  o[1] = f2bf((v.y - mu) * rs * gv.y + bv.y);
  o[2] = f2bf((v.z - mu) * rs * gv.z + bv.z);
  o[3] = f2bf((v.w - mu) * rs * gv.w + bv.w);
  *(short4v*)(out + (size_t)row * DM + tid * 4) = o;
}

__global__ __launch_bounds__(256) void concat_bias_k(
    const float* __restrict__ bq, const float* __restrict__ bk,
    const float* __restrict__ bv, float* __restrict__ o)
{
  int i = blockIdx.x * 256 + threadIdx.x;
  if (i < 3072) {
    float v = (i < 1024) ? bq[i] : (i < 2048 ? bk[i - 1024] : bv[i - 2048]);
    o[i] = v;
  }
}

// ---------------------------------------------------------------------------
// V transpose: V region of QKV [token][h*64+d] -> Vt [(b*16+h)*64+d][2048]
// ---------------------------------------------------------------------------
__global__ __launch_bounds__(256) void vtrans_k(
    const short* __restrict__ V, short* __restrict__ Vt)
{
  const int b = blockIdx.z, h = blockIdx.y, t0 = blockIdx.x * 64;
  __shared__ short tile[64][72];
  const int tid = threadIdx.x;
  const int r = tid >> 2, c = (tid & 3) * 16;
  const short* src = V + (size_t)(b * SEQ + t0 + r) * LDQKV + h * 64 + c;
  *(short8*)&tile[r][c]     = *(const short8*)src;
  *(short8*)&tile[r][c + 8] = *(const short8*)(src + 8);
  __syncthreads();
  const int d = tid >> 2;
  short8 o0, o1;
#pragma unroll
  for (int k = 0; k < 8; k++) o0[k] = tile[c + k][d];
#pragma unroll
  for (int k = 0; k < 8; k++) o1[k] = tile[c + 8 + k][d];
  short* dst = Vt + (((size_t)(b * 16 + h) * 64) + d) * 2048 + t0 + c;
  *(short8*)dst       = o0;
  *(short8*)(dst + 8) = o1;
}

// ---------------------------------------------------------------------------
// GEMM: C[M,N] = A[M,K](bf16) * Bt[N,K](bf16)^T + bias (+gelu) (+resid)
// 128x128 tile, BK=32, 4 waves (2x2 of 64x64), global_load_lds staging.
// ---------------------------------------------------------------------------
template <bool GELU_, bool RESID, bool OUTBF16>
__global__ __launch_bounds__(256) void gemm_bt(
    const short* __restrict__ A, const short* __restrict__ Bt,
    const float* __restrict__ bias, const float* __restrict__ resid,
    void* __restrict__ Cout, int M, int N, int K)
{
  __shared__ __align__(16) short Abuf[128 * 32];
  __shared__ __align__(16) short Bbuf[128 * 32];
  const int tid = threadIdx.x, lane = tid & 63, wid = tid >> 6;
  const int wr = wid >> 1, wc = wid & 1;
  const int bm = blockIdx.x * 128, bn = blockIdx.y * 128;

  f32x4 acc[4][4] = {};

  const int arow  = wid * 32 + (lane >> 2);
  const int acol8 = (lane & 3) * 8;
  const short* Ag0 = A  + (size_t)(bm + arow)      * K + acol8;
  const short* Ag1 = A  + (size_t)(bm + arow + 16) * K + acol8;
  const short* Bg0 = Bt + (size_t)(bn + arow)      * K + acol8;
  const short* Bg1 = Bt + (size_t)(bn + arow + 16) * K + acol8;
  short* Al0 = &Abuf[(wid * 32) * 32];
  short* Al1 = &Abuf[(wid * 32 + 16) * 32];
  short* Bl0 = &Bbuf[(wid * 32) * 32];
  short* Bl1 = &Bbuf[(wid * 32 + 16) * 32];

  for (int k0 = 0; k0 < K; k0 += 32) {
    gl_lds16(Ag0 + k0, Al0);
    gl_lds16(Ag1 + k0, Al1);
    gl_lds16(Bg0 + k0, Bl0);
    gl_lds16(Bg1 + k0, Bl1);
    __syncthreads();
    bf16x8 a[4], b[4];
#pragma unroll
    for (int mi = 0; mi < 4; mi++)
      a[mi] = *(const bf16x8*)&Abuf[(wr * 64 + mi * 16 + (lane & 15)) * 32 + (lane >> 4) * 8];
#pragma unroll
    for (int ni = 0; ni < 4; ni++)
      b[ni] = *(const bf16x8*)&Bbuf[(wc * 64 + ni * 16 + (lane & 15)) * 32 + (lane >> 4) * 8];
#pragma unroll
    for (int mi = 0; mi < 4; mi++)
#pragma unroll
      for (int ni = 0; ni < 4; ni++)
        acc[mi][ni] = mfma_bf16(a[mi], b[ni], acc[mi][ni]);
    __syncthreads();
  }

#pragma unroll
  for (int mi = 0; mi < 4; mi++) {
#pragma unroll
    for (int ni = 0; ni < 4; ni++) {
      const int col = bn + wc * 64 + ni * 16 + (lane & 15);
      const float bs = bias[col];
#pragma unroll
      for (int j = 0; j < 4; j++) {
        const int row = bm + wr * 64 + mi * 16 + (lane >> 4) * 4 + j;
        float v = acc[mi][ni][j] + bs;
        if (GELU_) v = 0.5f * v * (1.0f + erff(v * 0.70710678118654752f));
        if (RESID) v += resid[(size_t)row * N + col];
        if (OUTBF16) ((short*)Cout)[(size_t)row * N + col] = f2bf(v);
        else         ((float*)Cout)[(size_t)row * N + col] = v;
      }
    }
  }
}

// ---------------------------------------------------------------------------
// Flash attention, swapped-QK^T design.
// Block: (b, h, 64 q-rows), 4 waves x 16 q-rows. KV tile = 64 keys.
// K staged [key][d] via gload_lds w/ pre-swizzled source; V from global Vt
// [d][t] staged [d][key] the same way. S^T = mfma(K,Q): lane owns a full
// q-row -> in-lane softmax + shfl_xor(16,32). P through per-wave LDS as
// 8B writes / 16B reads, XOR-swizzled.
// ---------------------------------------------------------------------------
__global__ __launch_bounds__(256) void attn_k(
    const short* __restrict__ Qg, const short* __restrict__ Kg,
    const short* __restrict__ Vt, short* __restrict__ Og)
{
  const int b = blockIdx.z, h = blockIdx.y, q0 = blockIdx.x * 64;
  const int tid = threadIdx.x, lane = tid & 63, w = tid >> 6;
  const int qlane = lane & 15, g = lane >> 4;

  __shared__ __align__(16) short Kl[64 * 64];       // [key][d] swizzled
  __shared__ __align__(16) short Vl[64 * 64];       // [d][key] swizzled
  __shared__ __align__(16) short Pl[4][16 * 64];    // per-wave [q][key] swizzled

  char* KbC = (char*)Kl;
  char* VbC = (char*)Vl;
  char* PbC = (char*)&Pl[w][0];

  // Q fragments (B-operand): q = q0 + w*16 + qlane, k-dim = g*8..+7 (+32)
  const size_t qrow = (size_t)(b * SEQ + q0 + w * 16 + qlane) * LDQKV + h * 64;
  const bf16x8 qf0 = *(const bf16x8*)&Qg[qrow + g * 8];
  const bf16x8 qf1 = *(const bf16x8*)&Qg[qrow + 32 + g * 8];

  // staging constants: rows r = i*32 + w*8 + (lane>>3), slot = (lane&7)^(r&7)
  const int srow  = w * 8 + (lane >> 3);
  const int sslot = (lane & 7) ^ ((lane >> 3) & 7);
  const short* Kg_base = Kg + (size_t)(b * SEQ) * LDQKV + h * 64 + sslot * 8;
  const short* Vt_base = Vt + ((size_t)(b * 16 + h) * 64 + srow) * 2048 + sslot * 8;

  float m_run = -1e30f, l_run = 0.f;
  f32x4 oacc[4] = {};
  const float C = 0.125f * 1.44269504088896f;   // head-scale * log2(e)

  for (int kt = 0; kt < SEQ; kt += 64) {
    // ---- stage K [64 keys][64 d] and V^T [64 d][64 keys]
    const short* Kt0 = Kg_base + (size_t)(kt + srow) * LDQKV;
    gl_lds16(Kt0,                         &Kl[(w * 8) * 64]);
    gl_lds16(Kt0 + (size_t)32 * LDQKV,    &Kl[(32 + w * 8) * 64]);
    const short* Vt0 = Vt_base + kt;
    gl_lds16(Vt0,                         &Vl[(w * 8) * 64]);
    gl_lds16(Vt0 + (size_t)32 * 2048,     &Vl[(32 + w * 8) * 64]);
    __syncthreads();

    // ---- S^T = mfma(K, Q): s[kc][j] = S[q=qlane][key=16kc+4g+j]
    f32x4 s[4];
#pragma unroll
    for (int kc = 0; kc < 4; kc++) {
      const int kr = kc * 16 + qlane;
      const char* kp = KbC + kr * 128;
      const int sw = (kr & 7) << 4;
      bf16x8 kf0 = *(const bf16x8*)(kp + ((g * 16) ^ sw));
      bf16x8 kf1 = *(const bf16x8*)(kp + ((64 + g * 16) ^ sw));
      f32x4 z = {};
      z = mfma_bf16(kf0, qf0, z);
      z = mfma_bf16(kf1, qf1, z);
      s[kc] = z;
    }

    // ---- online softmax for q = qlane (lane group {q, q+16, q+32, q+48})
    f32x4 mx = s[0];
    mx = (f32x4){fmaxf(mx[0], s[1][0]), fmaxf(mx[1], s[1][1]), fmaxf(mx[2], s[1][2]), fmaxf(mx[3], s[1][3])};
    mx = (f32x4){fmaxf(mx[0], s[2][0]), fmaxf(mx[1], s[2][1]), fmaxf(mx[2], s[2][2]), fmaxf(mx[3], s[2][3])};
    mx = (f32x4){fmaxf(mx[0], s[3][0]), fmaxf(mx[1], s[3][1]), fmaxf(mx[2], s[3][2]), fmaxf(mx[3], s[3][3])};
    float mt = fmaxf(fmaxf(mx[0], mx[1]), fmaxf(mx[2], mx[3]));
    mt = fmaxf(mt, __shfl_xor(mt, 16));
    mt = fmaxf(mt, __shfl_xor(mt, 32));
    const float mnew = fmaxf(m_run, mt);
    const float r = exp2f((m_run - mnew) * C);
    m_run = mnew;

    float rs = 0.f;
    const int psw = (qlane & 7) << 4;
#pragma unroll
    for (int kc = 0; kc < 4; kc++) {
      f32x4 p;
#pragma unroll
      for (int j = 0; j < 4; j++) p[j] = exp2f((s[kc][j] - mnew) * C);
      rs += p[0] + p[1] + p[2] + p[3];
      short4v pk;
      pk[0] = f2bf(p[0]); pk[1] = f2bf(p[1]); pk[2] = f2bf(p[2]); pk[3] = f2bf(p[3]);
      *(short4v*)(PbC + qlane * 128 + ((32 * kc + 8 * g) ^ psw)) = pk;
    }
    rs += __shfl_xor(rs, 16);
    rs += __shfl_xor(rs, 32);
    l_run = l_run * r + rs;

    // rescale O (rows q = 4g+j need r of lane 4g+j)
#pragma unroll
    for (int j = 0; j < 4; j++) {
      const float rj = __shfl(r, g * 4 + j);
#pragma unroll
      for (int dt = 0; dt < 4; dt++) oacc[dt][j] *= rj;
    }

    // ---- PV: O[q][d] += P[q][key] * Vt[d][key]
#pragma unroll
    for (int ks = 0; ks < 2; ks++) {
      bf16x8 pf = *(const bf16x8*)(PbC + qlane * 128 + ((64 * ks + 16 * g) ^ psw));
#pragma unroll
      for (int dt = 0; dt < 4; dt++) {
        const int vr = dt * 16 + qlane;
        bf16x8 vf = *(const bf16x8*)(VbC + vr * 128 + ((64 * ks + 16 * g) ^ ((vr & 7) << 4)));
        oacc[dt] = mfma_bf16(pf, vf, oacc[dt]);
      }
    }
    __syncthreads();
  }

  // ---- epilogue
  const float linv = 1.f / l_run;
#pragma unroll
  for (int j = 0; j < 4; j++) {
    const float lj = __shfl(linv, g * 4 + j);
    const int tok = q0 + w * 16 + g * 4 + j;
#pragma unroll
    for (int dt = 0; dt < 4; dt++)
      Og[(size_t)(b * SEQ + tok) * DM + h * 64 + dt * 16 + qlane] = f2bf(oacc[dt][j] * lj);
  }
}

// ---------------------------------------------------------------------------
extern "C" void kernel_launch(void* const* d_in, const int* in_sizes, int n_in,
                              void* d_out, int out_size, void* d_ws, size_t ws_size,
                              hipStream_t stream)
{
  const float* x    = (const float*)d_in[0];
  const float* Wq   = (const float*)d_in[1];
  const float* bq   = (const float*)d_in[2];
  const float* Wk   = (const float*)d_in[3];
  const float* bk   = (const float*)d_in[4];
  const float* Wv   = (const float*)d_in[5];
  const float* bv   = (const float*)d_in[6];
  const float* Wo   = (const float*)d_in[7];
  const float* bo   = (const float*)d_in[8];
  const float* W1   = (const float*)d_in[9];
  const float* b1   = (const float*)d_in[10];
  const float* W2   = (const float*)d_in[11];
  const float* b2   = (const float*)d_in[12];
  const float* ln1g = (const float*)d_in[13];
  const float* ln1b = (const float*)d_in[14];
  const float* ln2g = (const float*)d_in[15];
  const float* ln2b = (const float*)d_in[16];

  char* ws = (char*)d_ws;
  const size_t MB = 1024 * 1024;
  short* Wqkvt = (short*)(ws + 0 * MB);           // [3072][1024] bf16
  short* Wqt   = Wqkvt;
  short* Wkt   = (short*)(ws + 2 * MB);
  short* Wvt   = (short*)(ws + 4 * MB);
  short* Wot   = (short*)(ws + 6 * MB);           // [1024][1024]
  short* W1t   = (short*)(ws + 8 * MB);           // [4096][1024]
  short* W2t   = (short*)(ws + 16 * MB);          // [1024][4096]
  short* hbuf  = (short*)(ws + 24 * MB);          // [4096][1024] bf16
  short* QKV   = (short*)(ws + 32 * MB);          // [4096][3072] bf16
  short* AO    = (short*)(ws + 56 * MB);          // [4096][1024] bf16
  float* x1    = (float*)(ws + 64 * MB);          // [4096][1024] fp32 (after attn)
  short* Vtb   = (short*)(ws + 64 * MB);          // [2048][2048] bf16 Vt, dead before x1 written
  float* bqkv  = (float*)(ws + 80 * MB);          // [3072] fp32
  short* gbuf  = (short*)(ws + 32 * MB);          // [4096][4096] bf16, aliases QKV+AO

  dim3 tb(256);

  transpose_cast_k<<<dim3(32, 32),  tb, 0, stream>>>(Wq, Wqt, 1024, 1024);
  transpose_cast_k<<<dim3(32, 32),  tb, 0, stream>>>(Wk, Wkt, 1024, 1024);
  transpose_cast_k<<<dim3(32, 32),  tb, 0, stream>>>(Wv, Wvt, 1024, 1024);
  transpose_cast_k<<<dim3(32, 32),  tb, 0, stream>>>(Wo, Wot, 1024, 1024);
  transpose_cast_k<<<dim3(128, 32), tb, 0, stream>>>(W1, W1t, 1024, 4096);
  transpose_cast_k<<<dim3(32, 128), tb, 0, stream>>>(W2, W2t, 4096, 1024);
  concat_bias_k<<<dim3(12), tb, 0, stream>>>(bq, bk, bv, bqkv);

  // LN1
  ln_k<<<dim3(MTOK), tb, 0, stream>>>(x, ln1g, ln1b, hbuf);

  // fused QKV projection: [4096,1024] x [3072,1024]^T -> [4096,3072] bf16
  gemm_bt<false, false, true><<<dim3(32, 24), tb, 0, stream>>>(
      hbuf, Wqkvt, bqkv, nullptr, QKV, MTOK, 3072, 1024);

  // V transpose -> Vt [(b*16+h)*64+d][2048]
  vtrans_k<<<dim3(32, 16, 2), tb, 0, stream>>>(QKV + 2048, Vtb);

  // attention
  attn_k<<<dim3(32, 16, 2), tb, 0, stream>>>(QKV, QKV + 1024, Vtb, AO);

  // O-projection + residual: x1 = x + AO @ Wo + bo  (fp32 out)
  gemm_bt<false, true, false><<<dim3(32, 8), tb, 0, stream>>>(
      AO, Wot, bo, x, x1, MTOK, 1024, 1024);

  // LN2
  ln_k<<<dim3(MTOK), tb, 0, stream>>>(x1, ln2g, ln2b, hbuf);

  // FFN1 + GELU: [4096,1024] x [4096,1024]^T -> [4096,4096] bf16
  gemm_bt<true, false, true><<<dim3(32, 32), tb, 0, stream>>>(
      hbuf, W1t, b1, nullptr, gbuf, MTOK, 4096, 1024);

  // FFN2 + residual -> d_out fp32
  gemm_bt<false, true, false><<<dim3(32, 8), tb, 0, stream>>>(
      gbuf, W2t, b2, x1, (float*)d_out, MTOK, 1024, 4096);
}

// Round 3
// 357.932 us; speedup vs baseline: 1.1979x; 1.0249x over previous
//
#include <hip/hip_runtime.h>
#include <math.h>

#define SEQ   2048
#define DM    1024
#define LDQKV 3072
#define MTOK  4096   // B*T

typedef float  f32x4   __attribute__((ext_vector_type(4)));
typedef __bf16 bf16x8  __attribute__((ext_vector_type(8)));
typedef short  short8  __attribute__((ext_vector_type(8)));
typedef short  short4v __attribute__((ext_vector_type(4)));

__device__ __forceinline__ short f2bf(float f) {
  union { float f; unsigned u; } v; v.f = f;
  unsigned r = v.u + 0x7fffu + ((v.u >> 16) & 1u);
  return (short)(r >> 16);
}

__device__ __forceinline__ void gl_lds16(const void* g, void* l) {
  __builtin_amdgcn_global_load_lds(
      (const __attribute__((address_space(1))) void*)g,
      (__attribute__((address_space(3))) void*)l, 16, 0, 0);
}

__device__ __forceinline__ f32x4 mfma_bf16(bf16x8 a, bf16x8 b, f32x4 c) {
  return __builtin_amdgcn_mfma_f32_16x16x32_bf16(a, b, c, 0, 0, 0);
}

// ---------------------------------------------------------------------------
// Weight cast+transpose: W [K,N] fp32 -> Wt [N,K] bf16
// ---------------------------------------------------------------------------
__global__ __launch_bounds__(256) void transpose_cast_k(
    const float* __restrict__ W, short* __restrict__ Wt, int K, int N)
{
  __shared__ float tile[32][33];
  const int n0 = blockIdx.x * 32, k0 = blockIdx.y * 32;
  const int tx = threadIdx.x & 31, ty = threadIdx.x >> 5;   // 32 x 8
#pragma unroll
  for (int i = 0; i < 4; i++)
    tile[ty + i * 8][tx] = W[(size_t)(k0 + ty + i * 8) * N + n0 + tx];
  __syncthreads();
#pragma unroll
  for (int i = 0; i < 4; i++)
    Wt[(size_t)(n0 + ty + i * 8) * K + k0 + tx] = f2bf(tile[tx][ty + i * 8]);
}

// ---------------------------------------------------------------------------
// LayerNorm row kernel: x fp32 [rows,1024] -> out bf16
// ---------------------------------------------------------------------------
__global__ __launch_bounds__(256) void ln_k(
    const float* __restrict__ x, const float* __restrict__ g,
    const float* __restrict__ b, short* __restrict__ out)
{
  const int row = blockIdx.x;
  const int tid = threadIdx.x;
  const float4 v = ((const float4*)(x + (size_t)row * DM))[tid];
  float s  = v.x + v.y + v.z + v.w;
  float ss = v.x * v.x + v.y * v.y + v.z * v.z + v.w * v.w;
#pragma unroll
  for (int m = 32; m >= 1; m >>= 1) { s += __shfl_xor(s, m); ss += __shfl_xor(ss, m); }
  __shared__ float red[8];
  const int wid = tid >> 6;
  if ((tid & 63) == 0) { red[wid] = s; red[4 + wid] = ss; }
  __syncthreads();
  s  = red[0] + red[1] + red[2] + red[3];
  ss = red[4] + red[5] + red[6] + red[7];
  const float mu  = s * (1.f / DM);
  const float var = ss * (1.f / DM) - mu * mu;
  const float rs  = rsqrtf(var + 1e-5f);
  const float4 gv = ((const float4*)g)[tid];
  const float4 bv = ((const float4*)b)[tid];
  short4v o;
  o[0] = f2bf((v.x - mu) * rs * gv.x + bv.x);
  o[1] = f2bf((v.y - mu) * rs * gv.y + bv.y);
  o[2] = f2bf((v.z - mu) * rs * gv.z + bv.z);
  o[3] = f2bf((v.w - mu) * rs * gv.w + bv.w);
  *(short4v*)(out + (size_t)row * DM + tid * 4) = o;
}

__global__ __launch_bounds__(256) void concat_bias_k(
    const float* __restrict__ bq, const float* __restrict__ bk,
    const float* __restrict__ bv, float* __restrict__ o)
{
  int i = blockIdx.x * 256 + threadIdx.x;
  if (i < 3072) {
    float v = (i < 1024) ? bq[i] : (i < 2048 ? bk[i - 1024] : bv[i - 2048]);
    o[i] = v;
  }
}

// ---------------------------------------------------------------------------
// V transpose: V region of QKV [token][h*64+d] -> Vt [(b*16+h)*64+d][2048]
// ---------------------------------------------------------------------------
__global__ __launch_bounds__(256) void vtrans_k(
    const short* __restrict__ V, short* __restrict__ Vt)
{
  const int b = blockIdx.z, h = blockIdx.y, t0 = blockIdx.x * 64;
  __shared__ short tile[64][72];
  const int tid = threadIdx.x;
  const int r = tid >> 2, c = (tid & 3) * 16;
  const short* src = V + (size_t)(b * SEQ + t0 + r) * LDQKV + h * 64 + c;
  *(short8*)&tile[r][c]     = *(const short8*)src;
  *(short8*)&tile[r][c + 8] = *(const short8*)(src + 8);
  __syncthreads();
  const int d = tid >> 2;
  short8 o0, o1;
#pragma unroll
  for (int k = 0; k < 8; k++) o0[k] = tile[c + k][d];
#pragma unroll
  for (int k = 0; k < 8; k++) o1[k] = tile[c + 8 + k][d];
  short* dst = Vt + (((size_t)(b * 16 + h) * 64) + d) * 2048 + t0 + c;
  *(short8*)dst       = o0;
  *(short8*)(dst + 8) = o1;
}

// ---------------------------------------------------------------------------
// GEMM: C[M,N] = A[M,K](bf16) * Bt[N,K](bf16)^T + bias (+gelu) (+resid)
// 128x128 tile, BK=32, 4 waves (2x2 of 64x64).
// Double-buffered LDS: stage tile t+1 (global_load_lds) BEFORE computing
// tile t, single __syncthreads per K-step -> the barrier drain only waits on
// loads that overlapped the whole MFMA phase. Rescues 1-block/CU shapes.
// ---------------------------------------------------------------------------
template <bool GELU_, bool RESID, bool OUTBF16>
__global__ __launch_bounds__(256) void gemm_bt(
    const short* __restrict__ A, const short* __restrict__ Bt,
    const float* __restrict__ bias, const float* __restrict__ resid,
    void* __restrict__ Cout, int M, int N, int K)
{
  __shared__ __align__(16) short Abuf[2][128 * 32];
  __shared__ __align__(16) short Bbuf[2][128 * 32];
  const int tid = threadIdx.x, lane = tid & 63, wid = tid >> 6;
  const int wr = wid >> 1, wc = wid & 1;
  const int bm = blockIdx.x * 128, bn = blockIdx.y * 128;

  f32x4 acc[4][4] = {};

  const int arow  = wid * 32 + (lane >> 2);
  const int acol8 = (lane & 3) * 8;
  const short* Ag0 = A  + (size_t)(bm + arow)      * K + acol8;
  const short* Ag1 = A  + (size_t)(bm + arow + 16) * K + acol8;
  const short* Bg0 = Bt + (size_t)(bn + arow)      * K + acol8;
  const short* Bg1 = Bt + (size_t)(bn + arow + 16) * K + acol8;

  const int l0 = (wid * 32) * 32, l1 = (wid * 32 + 16) * 32;

  // prologue: stage tile 0 into buf 0
  gl_lds16(Ag0, &Abuf[0][l0]);
  gl_lds16(Ag1, &Abuf[0][l1]);
  gl_lds16(Bg0, &Bbuf[0][l0]);
  gl_lds16(Bg1, &Bbuf[0][l1]);
  __syncthreads();

  int cur = 0;
  for (int k0 = 32; k0 < K; k0 += 32) {
    // stage next tile into the other buffer (overlaps with MFMA below)
    const int nxt = cur ^ 1;
    gl_lds16(Ag0 + k0, &Abuf[nxt][l0]);
    gl_lds16(Ag1 + k0, &Abuf[nxt][l1]);
    gl_lds16(Bg0 + k0, &Bbuf[nxt][l0]);
    gl_lds16(Bg1 + k0, &Bbuf[nxt][l1]);

    bf16x8 a[4], b[4];
#pragma unroll
    for (int mi = 0; mi < 4; mi++)
      a[mi] = *(const bf16x8*)&Abuf[cur][(wr * 64 + mi * 16 + (lane & 15)) * 32 + (lane >> 4) * 8];
#pragma unroll
    for (int ni = 0; ni < 4; ni++)
      b[ni] = *(const bf16x8*)&Bbuf[cur][(wc * 64 + ni * 16 + (lane & 15)) * 32 + (lane >> 4) * 8];
#pragma unroll
    for (int mi = 0; mi < 4; mi++)
#pragma unroll
      for (int ni = 0; ni < 4; ni++)
        acc[mi][ni] = mfma_bf16(a[mi], b[ni], acc[mi][ni]);

    __syncthreads();   // drains this iteration's prefetch; guards buf reuse
    cur = nxt;
  }

  // epilogue tile
  {
    bf16x8 a[4], b[4];
#pragma unroll
    for (int mi = 0; mi < 4; mi++)
      a[mi] = *(const bf16x8*)&Abuf[cur][(wr * 64 + mi * 16 + (lane & 15)) * 32 + (lane >> 4) * 8];
#pragma unroll
    for (int ni = 0; ni < 4; ni++)
      b[ni] = *(const bf16x8*)&Bbuf[cur][(wc * 64 + ni * 16 + (lane & 15)) * 32 + (lane >> 4) * 8];
#pragma unroll
    for (int mi = 0; mi < 4; mi++)
#pragma unroll
      for (int ni = 0; ni < 4; ni++)
        acc[mi][ni] = mfma_bf16(a[mi], b[ni], acc[mi][ni]);
  }

#pragma unroll
  for (int mi = 0; mi < 4; mi++) {
#pragma unroll
    for (int ni = 0; ni < 4; ni++) {
      const int col = bn + wc * 64 + ni * 16 + (lane & 15);
      const float bs = bias[col];
#pragma unroll
      for (int j = 0; j < 4; j++) {
        const int row = bm + wr * 64 + mi * 16 + (lane >> 4) * 4 + j;
        float v = acc[mi][ni][j] + bs;
        if (GELU_) v = 0.5f * v * (1.0f + erff(v * 0.70710678118654752f));
        if (RESID) v += resid[(size_t)row * N + col];
        if (OUTBF16) ((short*)Cout)[(size_t)row * N + col] = f2bf(v);
        else         ((float*)Cout)[(size_t)row * N + col] = v;
      }
    }
  }
}

// ---------------------------------------------------------------------------
// Flash attention, swapped-QK^T, KVBLK=128, defer-max (T13).
// Block: (b, h, 64 q-rows), 4 waves x 16 q-rows.
// K staged [128 key][64 d] (128B rows, ^(row&7)<<4); V^T staged [64 d][128 key]
// (256B rows, ^(row&15)<<4); both via gl_lds with pre-swizzled global source.
// S^T = mfma(K,Q): each lane owns a full q-row; in-lane softmax + 2 shfl.
// P via per-wave LDS (256B rows, ^(q&15)<<4), 8B writes / 16B reads.
// ---------------------------------------------------------------------------
__global__ __launch_bounds__(256) void attn_k(
    const short* __restrict__ Qg, const short* __restrict__ Kg,
    const short* __restrict__ Vt, short* __restrict__ Og)
{
  const int b = blockIdx.z, h = blockIdx.y, q0 = blockIdx.x * 64;
  const int tid = threadIdx.x, lane = tid & 63, w = tid >> 6;
  const int qlane = lane & 15, g = lane >> 4;

  __shared__ __align__(16) short Kl[128 * 64];      // 16 KB
  __shared__ __align__(16) short Vl[64 * 128];      // 16 KB
  __shared__ __align__(16) short Pl[4][16 * 128];   // 16 KB

  char* KbC = (char*)Kl;
  char* VbC = (char*)Vl;
  char* PbC = (char*)&Pl[w][0];

  const size_t qrow = (size_t)(b * SEQ + q0 + w * 16 + qlane) * LDQKV + h * 64;
  const bf16x8 qf0 = *(const bf16x8*)&Qg[qrow + g * 8];
  const bf16x8 qf1 = *(const bf16x8*)&Qg[qrow + 32 + g * 8];

  // K staging: per gl i, key rows i*32 + w*8 + (lane>>3); slot pre-swizzle
  const int srowK = w * 8 + (lane >> 3);
  const int kslot = (lane & 7) ^ ((lane >> 3) & 7);
  const short* Kg_base = Kg + ((size_t)(b * SEQ) + srowK) * LDQKV + h * 64 + kslot * 8;
  const short* Vt_head = Vt + ((size_t)(b * 16 + h) * 64) * 2048;

  float m_run = -1e30f, l_run = 0.f;
  f32x4 oacc[4] = {};
  const float C = 0.125f * 1.44269504088896f;   // head-scale * log2(e)

  for (int kt = 0; kt < SEQ; kt += 128) {
    // ---- stage K [128 k][64 d]
    const short* Kt0 = Kg_base + (size_t)kt * LDQKV;
#pragma unroll
    for (int i = 0; i < 4; i++)
      gl_lds16(Kt0 + (size_t)(i * 32) * LDQKV, &Kl[(i * 32 + w * 8) * 64]);
    // ---- stage V^T [64 d][128 k]; per gl i: rows w*16+i*4+(lane>>4)
#pragma unroll
    for (int i = 0; i < 4; i++) {
      const int dloc = i * 4 + (lane >> 4);          // (d & 15)
      const int vs = (lane & 15) ^ dloc;
      gl_lds16(Vt_head + (size_t)(w * 16 + dloc) * 2048 + kt + vs * 8,
               &Vl[(w * 16 + i * 4) * 128]);
    }
    __syncthreads();

    // ---- S^T = mfma(K, Q): s[kc][j] = S[q=qlane][key=16kc+4g+j]
    f32x4 s[8];
#pragma unroll
    for (int kc = 0; kc < 8; kc++) {
      const int kr = kc * 16 + qlane;
      const char* kp = KbC + kr * 128;
      const int sw = (kr & 7) << 4;
      bf16x8 kf0 = *(const bf16x8*)(kp + ((g * 16) ^ sw));
      bf16x8 kf1 = *(const bf16x8*)(kp + ((64 + g * 16) ^ sw));
      f32x4 z = {};
      z = mfma_bf16(kf0, qf0, z);
      z = mfma_bf16(kf1, qf1, z);
      s[kc] = z;
    }

    // ---- tile max (in-lane tree + 2 shfl)
    f32x4 m4 = s[0];
#pragma unroll
    for (int kc = 1; kc < 8; kc++) {
      m4[0] = fmaxf(m4[0], s[kc][0]); m4[1] = fmaxf(m4[1], s[kc][1]);
      m4[2] = fmaxf(m4[2], s[kc][2]); m4[3] = fmaxf(m4[3], s[kc][3]);
    }
    float mt = fmaxf(fmaxf(m4[0], m4[1]), fmaxf(m4[2], m4[3]));
    mt = fmaxf(mt, __shfl_xor(mt, 16));
    mt = fmaxf(mt, __shfl_xor(mt, 32));

    // ---- defer-max: only rescale when some row's max grew by > 40 (raw)
    if (!__all(mt - m_run <= 40.0f)) {
      const float mnew = fmaxf(m_run, mt);
      const float r = exp2f((m_run - mnew) * C);
      m_run = mnew;
      l_run *= r;
#pragma unroll
      for (int j = 0; j < 4; j++) {
        const float rj = __shfl(r, g * 4 + j);
#pragma unroll
        for (int dt = 0; dt < 4; dt++) oacc[dt][j] *= rj;
      }
    }

    // ---- P = exp2(s*C - m*C), row-sum, pack to LDS
    const float nmc = -m_run * C;
    float rs = 0.f;
    const int psw = (qlane & 15) << 4;
#pragma unroll
    for (int kc = 0; kc < 8; kc++) {
      f32x4 p;
#pragma unroll
      for (int j = 0; j < 4; j++) p[j] = exp2f(fmaf(s[kc][j], C, nmc));
      rs += (p[0] + p[1]) + (p[2] + p[3]);
      short4v pk;
      pk[0] = f2bf(p[0]); pk[1] = f2bf(p[1]); pk[2] = f2bf(p[2]); pk[3] = f2bf(p[3]);
      *(short4v*)(PbC + qlane * 256 + ((32 * kc + 8 * g) ^ psw)) = pk;
    }
    rs += __shfl_xor(rs, 16);
    rs += __shfl_xor(rs, 32);
    l_run += rs;

    // ---- PV: O[q][d] += P[q][k] * Vt[d][k], 4 k-chunks of 32
#pragma unroll
    for (int ks = 0; ks < 4; ks++) {
      bf16x8 pf = *(const bf16x8*)(PbC + qlane * 256 + ((64 * ks + 16 * g) ^ psw));
#pragma unroll
      for (int dt = 0; dt < 4; dt++) {
        const int vr = dt * 16 + qlane;
        bf16x8 vf = *(const bf16x8*)(VbC + vr * 256 + ((64 * ks + 16 * g) ^ ((vr & 15) << 4)));
        oacc[dt] = mfma_bf16(pf, vf, oacc[dt]);
      }
    }
    __syncthreads();
  }

  // ---- epilogue
  const float linv = 1.f / l_run;
#pragma unroll
  for (int j = 0; j < 4; j++) {
    const float lj = __shfl(linv, g * 4 + j);
    const int tok = q0 + w * 16 + g * 4 + j;
#pragma unroll
    for (int dt = 0; dt < 4; dt++)
      Og[(size_t)(b * SEQ + tok) * DM + h * 64 + dt * 16 + qlane] = f2bf(oacc[dt][j] * lj);
  }
}

// ---------------------------------------------------------------------------
extern "C" void kernel_launch(void* const* d_in, const int* in_sizes, int n_in,
                              void* d_out, int out_size, void* d_ws, size_t ws_size,
                              hipStream_t stream)
{
  const float* x    = (const float*)d_in[0];
  const float* Wq   = (const float*)d_in[1];
  const float* bq   = (const float*)d_in[2];
  const float* Wk   = (const float*)d_in[3];
  const float* bk   = (const float*)d_in[4];
  const float* Wv   = (const float*)d_in[5];
  const float* bv   = (const float*)d_in[6];
  const float* Wo   = (const float*)d_in[7];
  const float* bo   = (const float*)d_in[8];
  const float* W1   = (const float*)d_in[9];
  const float* b1   = (const float*)d_in[10];
  const float* W2   = (const float*)d_in[11];
  const float* b2   = (const float*)d_in[12];
  const float* ln1g = (const float*)d_in[13];
  const float* ln1b = (const float*)d_in[14];
  const float* ln2g = (const float*)d_in[15];
  const float* ln2b = (const float*)d_in[16];

  char* ws = (char*)d_ws;
  const size_t MB = 1024 * 1024;
  short* Wqkvt = (short*)(ws + 0 * MB);           // [3072][1024] bf16
  short* Wqt   = Wqkvt;
  short* Wkt   = (short*)(ws + 2 * MB);
  short* Wvt   = (short*)(ws + 4 * MB);
  short* Wot   = (short*)(ws + 6 * MB);           // [1024][1024]
  short* W1t   = (short*)(ws + 8 * MB);           // [4096][1024]
  short* W2t   = (short*)(ws + 16 * MB);          // [1024][4096]
  short* hbuf  = (short*)(ws + 24 * MB);          // [4096][1024] bf16
  short* QKV   = (short*)(ws + 32 * MB);          // [4096][3072] bf16
  short* AO    = (short*)(ws + 56 * MB);          // [4096][1024] bf16
  float* x1    = (float*)(ws + 64 * MB);          // [4096][1024] fp32 (after attn)
  short* Vtb   = (short*)(ws + 64 * MB);          // [2048][2048] bf16 Vt, dead before x1 written
  float* bqkv  = (float*)(ws + 80 * MB);          // [3072] fp32
  short* gbuf  = (short*)(ws + 32 * MB);          // [4096][4096] bf16, aliases QKV+AO

  dim3 tb(256);

  transpose_cast_k<<<dim3(32, 32),  tb, 0, stream>>>(Wq, Wqt, 1024, 1024);
  transpose_cast_k<<<dim3(32, 32),  tb, 0, stream>>>(Wk, Wkt, 1024, 1024);
  transpose_cast_k<<<dim3(32, 32),  tb, 0, stream>>>(Wv, Wvt, 1024, 1024);
  transpose_cast_k<<<dim3(32, 32),  tb, 0, stream>>>(Wo, Wot, 1024, 1024);
  transpose_cast_k<<<dim3(128, 32), tb, 0, stream>>>(W1, W1t, 1024, 4096);
  transpose_cast_k<<<dim3(32, 128), tb, 0, stream>>>(W2, W2t, 4096, 1024);
  concat_bias_k<<<dim3(12), tb, 0, stream>>>(bq, bk, bv, bqkv);

  // LN1
  ln_k<<<dim3(MTOK), tb, 0, stream>>>(x, ln1g, ln1b, hbuf);

  // fused QKV projection: [4096,1024] x [3072,1024]^T -> [4096,3072] bf16
  gemm_bt<false, false, true><<<dim3(32, 24), tb, 0, stream>>>(
      hbuf, Wqkvt, bqkv, nullptr, QKV, MTOK, 3072, 1024);

  // V transpose -> Vt [(b*16+h)*64+d][2048]
  vtrans_k<<<dim3(32, 16, 2), tb, 0, stream>>>(QKV + 2048, Vtb);

  // attention
  attn_k<<<dim3(32, 16, 2), tb, 0, stream>>>(QKV, QKV + 1024, Vtb, AO);

  // O-projection + residual: x1 = x + AO @ Wo + bo  (fp32 out)
  gemm_bt<false, true, false><<<dim3(32, 8), tb, 0, stream>>>(
      AO, Wot, bo, x, x1, MTOK, 1024, 1024);

  // LN2
  ln_k<<<dim3(MTOK), tb, 0, stream>>>(x1, ln2g, ln2b, hbuf);

  // FFN1 + GELU: [4096,1024] x [4096,1024]^T -> [4096,4096] bf16
  gemm_bt<true, false, true><<<dim3(32, 32), tb, 0, stream>>>(
      hbuf, W1t, b1, nullptr, gbuf, MTOK, 4096, 1024);

  // FFN2 + residual -> d_out fp32
  gemm_bt<false, true, false><<<dim3(32, 8), tb, 0, stream>>>(
      gbuf, W2t, b2, x1, (float*)d_out, MTOK, 1024, 4096);
}

// Round 4
// 316.141 us; speedup vs baseline: 1.3562x; 1.1322x over previous
//
#include <hip/hip_runtime.h>
#include <math.h>

#define SEQ   2048
#define DM    1024
#define LDQKV 3072
#define MTOK  4096   // B*T

typedef float  f32x4   __attribute__((ext_vector_type(4)));
typedef __bf16 bf16x8  __attribute__((ext_vector_type(8)));
typedef short  short8  __attribute__((ext_vector_type(8)));
typedef short  short4v __attribute__((ext_vector_type(4)));

__device__ __forceinline__ short f2bf(float f) {
  union { float f; unsigned u; } v; v.f = f;
  unsigned r = v.u + 0x7fffu + ((v.u >> 16) & 1u);
  return (short)(r >> 16);
}

__device__ __forceinline__ void gl_lds16(const void* g, void* l) {
  __builtin_amdgcn_global_load_lds(
      (const __attribute__((address_space(1))) void*)g,
      (__attribute__((address_space(3))) void*)l, 16, 0, 0);
}

__device__ __forceinline__ f32x4 mfma_bf16(bf16x8 a, bf16x8 b, f32x4 c) {
  return __builtin_amdgcn_mfma_f32_16x16x32_bf16(a, b, c, 0, 0, 0);
}

// ---------------------------------------------------------------------------
// Weight cast+transpose: W [K,N] fp32 -> Wt [N,K] bf16
// ---------------------------------------------------------------------------
__global__ __launch_bounds__(256) void transpose_cast_k(
    const float* __restrict__ W, short* __restrict__ Wt, int K, int N)
{
  __shared__ float tile[32][33];
  const int n0 = blockIdx.x * 32, k0 = blockIdx.y * 32;
  const int tx = threadIdx.x & 31, ty = threadIdx.x >> 5;   // 32 x 8
#pragma unroll
  for (int i = 0; i < 4; i++)
    tile[ty + i * 8][tx] = W[(size_t)(k0 + ty + i * 8) * N + n0 + tx];
  __syncthreads();
#pragma unroll
  for (int i = 0; i < 4; i++)
    Wt[(size_t)(n0 + ty + i * 8) * K + k0 + tx] = f2bf(tile[tx][ty + i * 8]);
}

// ---------------------------------------------------------------------------
// LayerNorm row kernel: x fp32 [rows,1024] -> out bf16
// ---------------------------------------------------------------------------
__global__ __launch_bounds__(256) void ln_k(
    const float* __restrict__ x, const float* __restrict__ g,
    const float* __restrict__ b, short* __restrict__ out)
{
  const int row = blockIdx.x;
  const int tid = threadIdx.x;
  const float4 v = ((const float4*)(x + (size_t)row * DM))[tid];
  float s  = v.x + v.y + v.z + v.w;
  float ss = v.x * v.x + v.y * v.y + v.z * v.z + v.w * v.w;
#pragma unroll
  for (int m = 32; m >= 1; m >>= 1) { s += __shfl_xor(s, m); ss += __shfl_xor(ss, m); }
  __shared__ float red[8];
  const int wid = tid >> 6;
  if ((tid & 63) == 0) { red[wid] = s; red[4 + wid] = ss; }
  __syncthreads();
  s  = red[0] + red[1] + red[2] + red[3];
  ss = red[4] + red[5] + red[6] + red[7];
  const float mu  = s * (1.f / DM);
  const float var = ss * (1.f / DM) - mu * mu;
  const float rs  = rsqrtf(var + 1e-5f);
  const float4 gv = ((const float4*)g)[tid];
  const float4 bv = ((const float4*)b)[tid];
  short4v o;
  o[0] = f2bf((v.x - mu) * rs * gv.x + bv.x);
  o[1] = f2bf((v.y - mu) * rs * gv.y + bv.y);
  o[2] = f2bf((v.z - mu) * rs * gv.z + bv.z);
  o[3] = f2bf((v.w - mu) * rs * gv.w + bv.w);
  *(short4v*)(out + (size_t)row * DM + tid * 4) = o;
}

__global__ __launch_bounds__(256) void concat_bias_k(
    const float* __restrict__ bq, const float* __restrict__ bk,
    const float* __restrict__ bv, float* __restrict__ o)
{
  int i = blockIdx.x * 256 + threadIdx.x;
  if (i < 3072) {
    float v = (i < 1024) ? bq[i] : (i < 2048 ? bk[i - 1024] : bv[i - 2048]);
    o[i] = v;
  }
}

// ---------------------------------------------------------------------------
// V transpose: V region of QKV [token][h*64+d] -> Vt [(b*16+h)*64+d][2048]
// ---------------------------------------------------------------------------
__global__ __launch_bounds__(256) void vtrans_k(
    const short* __restrict__ V, short* __restrict__ Vt)
{
  const int b = blockIdx.z, h = blockIdx.y, t0 = blockIdx.x * 64;
  __shared__ short tile[64][72];
  const int tid = threadIdx.x;
  const int r = tid >> 2, c = (tid & 3) * 16;
  const short* src = V + (size_t)(b * SEQ + t0 + r) * LDQKV + h * 64 + c;
  *(short8*)&tile[r][c]     = *(const short8*)src;
  *(short8*)&tile[r][c + 8] = *(const short8*)(src + 8);
  __syncthreads();
  const int d = tid >> 2;
  short8 o0, o1;
#pragma unroll
  for (int k = 0; k < 8; k++) o0[k] = tile[c + k][d];
#pragma unroll
  for (int k = 0; k < 8; k++) o1[k] = tile[c + 8 + k][d];
  short* dst = Vt + (((size_t)(b * 16 + h) * 64) + d) * 2048 + t0 + c;
  *(short8*)dst       = o0;
  *(short8*)(dst + 8) = o1;
}

// ---------------------------------------------------------------------------
// GEMM 128x128, BK=32, 4 waves, double-buffered (for wide-N shapes with
// >=3 blocks/CU: qkv, ffn1).
// ---------------------------------------------------------------------------
template <bool GELU_, bool RESID, bool OUTBF16>
__global__ __launch_bounds__(256) void gemm_bt(
    const short* __restrict__ A, const short* __restrict__ Bt,
    const float* __restrict__ bias, const float* __restrict__ resid,
    void* __restrict__ Cout, int M, int N, int K)
{
  __shared__ __align__(16) short Abuf[2][128 * 32];
  __shared__ __align__(16) short Bbuf[2][128 * 32];
  const int tid = threadIdx.x, lane = tid & 63, wid = tid >> 6;
  const int wr = wid >> 1, wc = wid & 1;
  const int bm = blockIdx.x * 128, bn = blockIdx.y * 128;

  f32x4 acc[4][4] = {};

  const int arow  = wid * 32 + (lane >> 2);
  const int acol8 = (lane & 3) * 8;
  const short* Ag0 = A  + (size_t)(bm + arow)      * K + acol8;
  const short* Ag1 = A  + (size_t)(bm + arow + 16) * K + acol8;
  const short* Bg0 = Bt + (size_t)(bn + arow)      * K + acol8;
  const short* Bg1 = Bt + (size_t)(bn + arow + 16) * K + acol8;

  const int l0 = (wid * 32) * 32, l1 = (wid * 32 + 16) * 32;

  gl_lds16(Ag0, &Abuf[0][l0]);
  gl_lds16(Ag1, &Abuf[0][l1]);
  gl_lds16(Bg0, &Bbuf[0][l0]);
  gl_lds16(Bg1, &Bbuf[0][l1]);
  __syncthreads();

  int cur = 0;
  for (int k0 = 32; k0 < K; k0 += 32) {
    const int nxt = cur ^ 1;
    gl_lds16(Ag0 + k0, &Abuf[nxt][l0]);
    gl_lds16(Ag1 + k0, &Abuf[nxt][l1]);
    gl_lds16(Bg0 + k0, &Bbuf[nxt][l0]);
    gl_lds16(Bg1 + k0, &Bbuf[nxt][l1]);

    bf16x8 a[4], b[4];
#pragma unroll
    for (int mi = 0; mi < 4; mi++)
      a[mi] = *(const bf16x8*)&Abuf[cur][(wr * 64 + mi * 16 + (lane & 15)) * 32 + (lane >> 4) * 8];
#pragma unroll
    for (int ni = 0; ni < 4; ni++)
      b[ni] = *(const bf16x8*)&Bbuf[cur][(wc * 64 + ni * 16 + (lane & 15)) * 32 + (lane >> 4) * 8];
#pragma unroll
    for (int mi = 0; mi < 4; mi++)
#pragma unroll
      for (int ni = 0; ni < 4; ni++)
        acc[mi][ni] = mfma_bf16(a[mi], b[ni], acc[mi][ni]);

    __syncthreads();
    cur = nxt;
  }

  {
    bf16x8 a[4], b[4];
#pragma unroll
    for (int mi = 0; mi < 4; mi++)
      a[mi] = *(const bf16x8*)&Abuf[cur][(wr * 64 + mi * 16 + (lane & 15)) * 32 + (lane >> 4) * 8];
#pragma unroll
    for (int ni = 0; ni < 4; ni++)
      b[ni] = *(const bf16x8*)&Bbuf[cur][(wc * 64 + ni * 16 + (lane & 15)) * 32 + (lane >> 4) * 8];
#pragma unroll
    for (int mi = 0; mi < 4; mi++)
#pragma unroll
      for (int ni = 0; ni < 4; ni++)
        acc[mi][ni] = mfma_bf16(a[mi], b[ni], acc[mi][ni]);
  }

#pragma unroll
  for (int mi = 0; mi < 4; mi++) {
#pragma unroll
    for (int ni = 0; ni < 4; ni++) {
      const int col = bn + wc * 64 + ni * 16 + (lane & 15);
      const float bs = bias[col];
#pragma unroll
      for (int j = 0; j < 4; j++) {
        const int row = bm + wr * 64 + mi * 16 + (lane >> 4) * 4 + j;
        float v = acc[mi][ni][j] + bs;
        if (GELU_) v = 0.5f * v * (1.0f + erff(v * 0.70710678118654752f));
        if (RESID) v += resid[(size_t)row * N + col];
        if (OUTBF16) ((short*)Cout)[(size_t)row * N + col] = f2bf(v);
        else         ((float*)Cout)[(size_t)row * N + col] = v;
      }
    }
  }
}

// ---------------------------------------------------------------------------
// GEMM for narrow-N latency-bound shapes (o-proj, ffn2): 128x64 tile,
// 512 threads = 8 waves = 2 k-groups of 4 waves. Group kg processes BK=32
// chunks kg, kg+2, kg+4, ... (each group double-buffered) -> per-CU wave
// count 4x the old kernel (2 blocks/CU x 8 waves), K-loop halved per wave.
// Cross-group reduction via LDS at the end; no extra HBM traffic.
// ---------------------------------------------------------------------------
template <bool GELU_, bool RESID, bool OUTBF16>
__global__ __launch_bounds__(512) void gemm_bt8(
    const short* __restrict__ A, const short* __restrict__ Bt,
    const float* __restrict__ bias, const float* __restrict__ resid,
    void* __restrict__ Cout, int M, int N, int K)
{
  __shared__ __align__(16) short Ab[2][2][128 * 32];   // [kg][buf] 32 KB
  __shared__ __align__(16) short Bb[2][2][64 * 32];    // [kg][buf] 16 KB
  const int tid = threadIdx.x, lane = tid & 63, wid = tid >> 6;
  const int kg = wid >> 2, w2 = wid & 3;
  const int wr = w2 >> 1, wc = w2 & 1;
  const int bm = blockIdx.x * 128, bn = blockIdx.y * 64;

  f32x4 acc[4][2] = {};

  const int r_l = lane >> 2;           // 0..15
  const int c8  = (lane & 3) * 8;
  const short* Ag0 = A  + (size_t)(bm + w2 * 32 + r_l)      * K + c8;
  const short* Ag1 = A  + (size_t)(bm + w2 * 32 + 16 + r_l) * K + c8;
  const short* Bg0 = Bt + (size_t)(bn + w2 * 16 + r_l)      * K + c8;

  const int la0 = (w2 * 32) * 32, la1 = (w2 * 32 + 16) * 32, lb0 = (w2 * 16) * 32;
  const int kbase = kg * 32;

  // prologue: group kg stages its chunk kg into buf 0
  gl_lds16(Ag0 + kbase, &Ab[kg][0][la0]);
  gl_lds16(Ag1 + kbase, &Ab[kg][0][la1]);
  gl_lds16(Bg0 + kbase, &Bb[kg][0][lb0]);
  __syncthreads();

  const int nsteps = K >> 6;   // chunks per group
  int cur = 0;
  for (int i = 1; i < nsteps; ++i) {
    const int k0 = i * 64 + kbase;
    const int nxt = cur ^ 1;
    gl_lds16(Ag0 + k0, &Ab[kg][nxt][la0]);
    gl_lds16(Ag1 + k0, &Ab[kg][nxt][la1]);
    gl_lds16(Bg0 + k0, &Bb[kg][nxt][lb0]);

    bf16x8 a[4], b[2];
#pragma unroll
    for (int mi = 0; mi < 4; mi++)
      a[mi] = *(const bf16x8*)&Ab[kg][cur][(wr * 64 + mi * 16 + (lane & 15)) * 32 + (lane >> 4) * 8];
#pragma unroll
    for (int ni = 0; ni < 2; ni++)
      b[ni] = *(const bf16x8*)&Bb[kg][cur][(wc * 32 + ni * 16 + (lane & 15)) * 32 + (lane >> 4) * 8];
#pragma unroll
    for (int mi = 0; mi < 4; mi++)
#pragma unroll
      for (int ni = 0; ni < 2; ni++)
        acc[mi][ni] = mfma_bf16(a[mi], b[ni], acc[mi][ni]);

    __syncthreads();
    cur = nxt;
  }

  // tail chunk
  {
    bf16x8 a[4], b[2];
#pragma unroll
    for (int mi = 0; mi < 4; mi++)
      a[mi] = *(const bf16x8*)&Ab[kg][cur][(wr * 64 + mi * 16 + (lane & 15)) * 32 + (lane >> 4) * 8];
#pragma unroll
    for (int ni = 0; ni < 2; ni++)
      b[ni] = *(const bf16x8*)&Bb[kg][cur][(wc * 32 + ni * 16 + (lane & 15)) * 32 + (lane >> 4) * 8];
#pragma unroll
    for (int mi = 0; mi < 4; mi++)
#pragma unroll
      for (int ni = 0; ni < 2; ni++)
        acc[mi][ni] = mfma_bf16(a[mi], b[ni], acc[mi][ni]);
  }

  __syncthreads();   // all LDS reads done before overlay reuse

  // cross-group reduction through LDS (overlay on Ab: 128x64 fp32 = 32 KB)
  float* red = (float*)&Ab[0][0][0];
  const int slot = (w2 * 64 + lane) * 8;
  if (kg == 1) {
#pragma unroll
    for (int mi = 0; mi < 4; mi++)
#pragma unroll
      for (int ni = 0; ni < 2; ni++)
        *(f32x4*)&red[(slot + mi * 2 + ni) * 4] = acc[mi][ni];
  }
  __syncthreads();
  if (kg == 0) {
#pragma unroll
    for (int mi = 0; mi < 4; mi++)
#pragma unroll
      for (int ni = 0; ni < 2; ni++)
        acc[mi][ni] += *(const f32x4*)&red[(slot + mi * 2 + ni) * 4];

#pragma unroll
    for (int mi = 0; mi < 4; mi++) {
#pragma unroll
      for (int ni = 0; ni < 2; ni++) {
        const int col = bn + wc * 32 + ni * 16 + (lane & 15);
        const float bs = bias[col];
#pragma unroll
        for (int j = 0; j < 4; j++) {
          const int row = bm + wr * 64 + mi * 16 + (lane >> 4) * 4 + j;
          float v = acc[mi][ni][j] + bs;
          if (GELU_) v = 0.5f * v * (1.0f + erff(v * 0.70710678118654752f));
          if (RESID) v += resid[(size_t)row * N + col];
          if (OUTBF16) ((short*)Cout)[(size_t)row * N + col] = f2bf(v);
          else         ((float*)Cout)[(size_t)row * N + col] = v;
        }
      }
    }
  }
}

// ---------------------------------------------------------------------------
// Flash attention, swapped-QK^T, KVBLK=128, defer-max (T13).
// ---------------------------------------------------------------------------
__global__ __launch_bounds__(256) void attn_k(
    const short* __restrict__ Qg, const short* __restrict__ Kg,
    const short* __restrict__ Vt, short* __restrict__ Og)
{
  const int b = blockIdx.z, h = blockIdx.y, q0 = blockIdx.x * 64;
  const int tid = threadIdx.x, lane = tid & 63, w = tid >> 6;
  const int qlane = lane & 15, g = lane >> 4;

  __shared__ __align__(16) short Kl[128 * 64];      // 16 KB
  __shared__ __align__(16) short Vl[64 * 128];      // 16 KB
  __shared__ __align__(16) short Pl[4][16 * 128];   // 16 KB

  char* KbC = (char*)Kl;
  char* VbC = (char*)Vl;
  char* PbC = (char*)&Pl[w][0];

  const size_t qrow = (size_t)(b * SEQ + q0 + w * 16 + qlane) * LDQKV + h * 64;
  const bf16x8 qf0 = *(const bf16x8*)&Qg[qrow + g * 8];
  const bf16x8 qf1 = *(const bf16x8*)&Qg[qrow + 32 + g * 8];

  const int srowK = w * 8 + (lane >> 3);
  const int kslot = (lane & 7) ^ ((lane >> 3) & 7);
  const short* Kg_base = Kg + ((size_t)(b * SEQ) + srowK) * LDQKV + h * 64 + kslot * 8;
  const short* Vt_head = Vt + ((size_t)(b * 16 + h) * 64) * 2048;

  float m_run = -1e30f, l_run = 0.f;
  f32x4 oacc[4] = {};
  const float C = 0.125f * 1.44269504088896f;   // head-scale * log2(e)

  for (int kt = 0; kt < SEQ; kt += 128) {
    const short* Kt0 = Kg_base + (size_t)kt * LDQKV;
#pragma unroll
    for (int i = 0; i < 4; i++)
      gl_lds16(Kt0 + (size_t)(i * 32) * LDQKV, &Kl[(i * 32 + w * 8) * 64]);
#pragma unroll
    for (int i = 0; i < 4; i++) {
      const int dloc = i * 4 + (lane >> 4);
      const int vs = (lane & 15) ^ dloc;
      gl_lds16(Vt_head + (size_t)(w * 16 + dloc) * 2048 + kt + vs * 8,
               &Vl[(w * 16 + i * 4) * 128]);
    }
    __syncthreads();

    f32x4 s[8];
#pragma unroll
    for (int kc = 0; kc < 8; kc++) {
      const int kr = kc * 16 + qlane;
      const char* kp = KbC + kr * 128;
      const int sw = (kr & 7) << 4;
      bf16x8 kf0 = *(const bf16x8*)(kp + ((g * 16) ^ sw));
      bf16x8 kf1 = *(const bf16x8*)(kp + ((64 + g * 16) ^ sw));
      f32x4 z = {};
      z = mfma_bf16(kf0, qf0, z);
      z = mfma_bf16(kf1, qf1, z);
      s[kc] = z;
    }

    f32x4 m4 = s[0];
#pragma unroll
    for (int kc = 1; kc < 8; kc++) {
      m4[0] = fmaxf(m4[0], s[kc][0]); m4[1] = fmaxf(m4[1], s[kc][1]);
      m4[2] = fmaxf(m4[2], s[kc][2]); m4[3] = fmaxf(m4[3], s[kc][3]);
    }
    float mt = fmaxf(fmaxf(m4[0], m4[1]), fmaxf(m4[2], m4[3]));
    mt = fmaxf(mt, __shfl_xor(mt, 16));
    mt = fmaxf(mt, __shfl_xor(mt, 32));

    if (!__all(mt - m_run <= 40.0f)) {
      const float mnew = fmaxf(m_run, mt);
      const float r = exp2f((m_run - mnew) * C);
      m_run = mnew;
      l_run *= r;
#pragma unroll
      for (int j = 0; j < 4; j++) {
        const float rj = __shfl(r, g * 4 + j);
#pragma unroll
        for (int dt = 0; dt < 4; dt++) oacc[dt][j] *= rj;
      }
    }

    const float nmc = -m_run * C;
    float rs = 0.f;
    const int psw = (qlane & 15) << 4;
#pragma unroll
    for (int kc = 0; kc < 8; kc++) {
      f32x4 p;
#pragma unroll
      for (int j = 0; j < 4; j++) p[j] = exp2f(fmaf(s[kc][j], C, nmc));
      rs += (p[0] + p[1]) + (p[2] + p[3]);
      short4v pk;
      pk[0] = f2bf(p[0]); pk[1] = f2bf(p[1]); pk[2] = f2bf(p[2]); pk[3] = f2bf(p[3]);
      *(short4v*)(PbC + qlane * 256 + ((32 * kc + 8 * g) ^ psw)) = pk;
    }
    rs += __shfl_xor(rs, 16);
    rs += __shfl_xor(rs, 32);
    l_run += rs;

#pragma unroll
    for (int ks = 0; ks < 4; ks++) {
      bf16x8 pf = *(const bf16x8*)(PbC + qlane * 256 + ((64 * ks + 16 * g) ^ psw));
#pragma unroll
      for (int dt = 0; dt < 4; dt++) {
        const int vr = dt * 16 + qlane;
        bf16x8 vf = *(const bf16x8*)(VbC + vr * 256 + ((64 * ks + 16 * g) ^ ((vr & 15) << 4)));
        oacc[dt] = mfma_bf16(pf, vf, oacc[dt]);
      }
    }
    __syncthreads();
  }

  const float linv = 1.f / l_run;
#pragma unroll
  for (int j = 0; j < 4; j++) {
    const float lj = __shfl(linv, g * 4 + j);
    const int tok = q0 + w * 16 + g * 4 + j;
#pragma unroll
    for (int dt = 0; dt < 4; dt++)
      Og[(size_t)(b * SEQ + tok) * DM + h * 64 + dt * 16 + qlane] = f2bf(oacc[dt][j] * lj);
  }
}

// ---------------------------------------------------------------------------
extern "C" void kernel_launch(void* const* d_in, const int* in_sizes, int n_in,
                              void* d_out, int out_size, void* d_ws, size_t ws_size,
                              hipStream_t stream)
{
  const float* x    = (const float*)d_in[0];
  const float* Wq   = (const float*)d_in[1];
  const float* bq   = (const float*)d_in[2];
  const float* Wk   = (const float*)d_in[3];
  const float* bk   = (const float*)d_in[4];
  const float* Wv   = (const float*)d_in[5];
  const float* bv   = (const float*)d_in[6];
  const float* Wo   = (const float*)d_in[7];
  const float* bo   = (const float*)d_in[8];
  const float* W1   = (const float*)d_in[9];
  const float* b1   = (const float*)d_in[10];
  const float* W2   = (const float*)d_in[11];
  const float* b2   = (const float*)d_in[12];
  const float* ln1g = (const float*)d_in[13];
  const float* ln1b = (const float*)d_in[14];
  const float* ln2g = (const float*)d_in[15];
  const float* ln2b = (const float*)d_in[16];

  char* ws = (char*)d_ws;
  const size_t MB = 1024 * 1024;
  short* Wqkvt = (short*)(ws + 0 * MB);           // [3072][1024] bf16
  short* Wqt   = Wqkvt;
  short* Wkt   = (short*)(ws + 2 * MB);
  short* Wvt   = (short*)(ws + 4 * MB);
  short* Wot   = (short*)(ws + 6 * MB);           // [1024][1024]
  short* W1t   = (short*)(ws + 8 * MB);           // [4096][1024]
  short* W2t   = (short*)(ws + 16 * MB);          // [1024][4096]
  short* hbuf  = (short*)(ws + 24 * MB);          // [4096][1024] bf16
  short* QKV   = (short*)(ws + 32 * MB);          // [4096][3072] bf16
  short* AO    = (short*)(ws + 56 * MB);          // [4096][1024] bf16
  float* x1    = (float*)(ws + 64 * MB);          // [4096][1024] fp32 (after attn)
  short* Vtb   = (short*)(ws + 64 * MB);          // [2048][2048] bf16 Vt, dead before x1 written
  float* bqkv  = (float*)(ws + 80 * MB);          // [3072] fp32
  short* gbuf  = (short*)(ws + 32 * MB);          // [4096][4096] bf16, aliases QKV+AO

  dim3 tb(256);

  transpose_cast_k<<<dim3(32, 32),  tb, 0, stream>>>(Wq, Wqt, 1024, 1024);
  transpose_cast_k<<<dim3(32, 32),  tb, 0, stream>>>(Wk, Wkt, 1024, 1024);
  transpose_cast_k<<<dim3(32, 32),  tb, 0, stream>>>(Wv, Wvt, 1024, 1024);
  transpose_cast_k<<<dim3(32, 32),  tb, 0, stream>>>(Wo, Wot, 1024, 1024);
  transpose_cast_k<<<dim3(128, 32), tb, 0, stream>>>(W1, W1t, 1024, 4096);
  transpose_cast_k<<<dim3(32, 128), tb, 0, stream>>>(W2, W2t, 4096, 1024);
  concat_bias_k<<<dim3(12), tb, 0, stream>>>(bq, bk, bv, bqkv);

  // LN1
  ln_k<<<dim3(MTOK), tb, 0, stream>>>(x, ln1g, ln1b, hbuf);

  // fused QKV projection: [4096,1024] x [3072,1024]^T -> [4096,3072] bf16
  gemm_bt<false, false, true><<<dim3(32, 24), tb, 0, stream>>>(
      hbuf, Wqkvt, bqkv, nullptr, QKV, MTOK, 3072, 1024);

  // V transpose -> Vt [(b*16+h)*64+d][2048]
  vtrans_k<<<dim3(32, 16, 2), tb, 0, stream>>>(QKV + 2048, Vtb);

  // attention
  attn_k<<<dim3(32, 16, 2), tb, 0, stream>>>(QKV, QKV + 1024, Vtb, AO);

  // O-projection + residual: x1 = x + AO @ Wo + bo  (fp32 out)  [8-wave k-split]
  gemm_bt8<false, true, false><<<dim3(32, 16), dim3(512), 0, stream>>>(
      AO, Wot, bo, x, x1, MTOK, 1024, 1024);

  // LN2
  ln_k<<<dim3(MTOK), tb, 0, stream>>>(x1, ln2g, ln2b, hbuf);

  // FFN1 + GELU: [4096,1024] x [4096,1024]^T -> [4096,4096] bf16
  gemm_bt<true, false, true><<<dim3(32, 32), tb, 0, stream>>>(
      hbuf, W1t, b1, nullptr, gbuf, MTOK, 4096, 1024);

  // FFN2 + residual -> d_out fp32  [8-wave k-split]
  gemm_bt8<false, true, false><<<dim3(32, 16), dim3(512), 0, stream>>>(
      gbuf, W2t, b2, x1, (float*)d_out, MTOK, 1024, 4096);
}

// Round 5
// 304.142 us; speedup vs baseline: 1.4097x; 1.0395x over previous
//
#include <hip/hip_runtime.h>
#include <math.h>

#define SEQ   2048
#define DM    1024
#define LDQKV 3072
#define MTOK  4096   // B*T

typedef float  f32x4   __attribute__((ext_vector_type(4)));
typedef __bf16 bf16x8  __attribute__((ext_vector_type(8)));
typedef short  short8  __attribute__((ext_vector_type(8)));
typedef short  short4v __attribute__((ext_vector_type(4)));

__device__ __forceinline__ short f2bf(float f) {
  union { float f; unsigned u; } v; v.f = f;
  unsigned r = v.u + 0x7fffu + ((v.u >> 16) & 1u);
  return (short)(r >> 16);
}

__device__ __forceinline__ void gl_lds16(const void* g, void* l) {
  __builtin_amdgcn_global_load_lds(
      (const __attribute__((address_space(1))) void*)g,
      (__attribute__((address_space(3))) void*)l, 16, 0, 0);
}

__device__ __forceinline__ f32x4 mfma_bf16(bf16x8 a, bf16x8 b, f32x4 c) {
  return __builtin_amdgcn_mfma_f32_16x16x32_bf16(a, b, c, 0, 0, 0);
}

// ---------------------------------------------------------------------------
// Weight cast+transpose: W [K,N] fp32 -> Wt [N,K] bf16
// ---------------------------------------------------------------------------
__global__ __launch_bounds__(256) void transpose_cast_k(
    const float* __restrict__ W, short* __restrict__ Wt, int K, int N)
{
  __shared__ float tile[32][33];
  const int n0 = blockIdx.x * 32, k0 = blockIdx.y * 32;
  const int tx = threadIdx.x & 31, ty = threadIdx.x >> 5;   // 32 x 8
#pragma unroll
  for (int i = 0; i < 4; i++)
    tile[ty + i * 8][tx] = W[(size_t)(k0 + ty + i * 8) * N + n0 + tx];
  __syncthreads();
#pragma unroll
  for (int i = 0; i < 4; i++)
    Wt[(size_t)(n0 + ty + i * 8) * K + k0 + tx] = f2bf(tile[tx][ty + i * 8]);
}

// ---------------------------------------------------------------------------
// LayerNorm row kernel: x fp32 [rows,1024] -> out bf16
// ---------------------------------------------------------------------------
__global__ __launch_bounds__(256) void ln_k(
    const float* __restrict__ x, const float* __restrict__ g,
    const float* __restrict__ b, short* __restrict__ out)
{
  const int row = blockIdx.x;
  const int tid = threadIdx.x;
  const float4 v = ((const float4*)(x + (size_t)row * DM))[tid];
  float s  = v.x + v.y + v.z + v.w;
  float ss = v.x * v.x + v.y * v.y + v.z * v.z + v.w * v.w;
#pragma unroll
  for (int m = 32; m >= 1; m >>= 1) { s += __shfl_xor(s, m); ss += __shfl_xor(ss, m); }
  __shared__ float red[8];
  const int wid = tid >> 6;
  if ((tid & 63) == 0) { red[wid] = s; red[4 + wid] = ss; }
  __syncthreads();
  s  = red[0] + red[1] + red[2] + red[3];
  ss = red[4] + red[5] + red[6] + red[7];
  const float mu  = s * (1.f / DM);
  const float var = ss * (1.f / DM) - mu * mu;
  const float rs  = rsqrtf(var + 1e-5f);
  const float4 gv = ((const float4*)g)[tid];
  const float4 bv = ((const float4*)b)[tid];
  short4v o;
  o[0] = f2bf((v.x - mu) * rs * gv.x + bv.x);
  o[1] = f2bf((v.y - mu) * rs * gv.y + bv.y);
  o[2] = f2bf((v.z - mu) * rs * gv.z + bv.z);
  o[3] = f2bf((v.w - mu) * rs * gv.w + bv.w);
  *(short4v*)(out + (size_t)row * DM + tid * 4) = o;
}

__global__ __launch_bounds__(256) void concat_bias_k(
    const float* __restrict__ bq, const float* __restrict__ bk,
    const float* __restrict__ bv, float* __restrict__ o)
{
  int i = blockIdx.x * 256 + threadIdx.x;
  if (i < 3072) {
    float v = (i < 1024) ? bq[i] : (i < 2048 ? bk[i - 1024] : bv[i - 2048]);
    o[i] = v;
  }
}

// ---------------------------------------------------------------------------
// V transpose: V region of QKV [token][h*64+d] -> Vt [(b*16+h)*64+d][2048]
// ---------------------------------------------------------------------------
__global__ __launch_bounds__(256) void vtrans_k(
    const short* __restrict__ V, short* __restrict__ Vt)
{
  const int b = blockIdx.z, h = blockIdx.y, t0 = blockIdx.x * 64;
  __shared__ short tile[64][72];
  const int tid = threadIdx.x;
  const int r = tid >> 2, c = (tid & 3) * 16;
  const short* src = V + (size_t)(b * SEQ + t0 + r) * LDQKV + h * 64 + c;
  *(short8*)&tile[r][c]     = *(const short8*)src;
  *(short8*)&tile[r][c + 8] = *(const short8*)(src + 8);
  __syncthreads();
  const int d = tid >> 2;
  short8 o0, o1;
#pragma unroll
  for (int k = 0; k < 8; k++) o0[k] = tile[c + k][d];
#pragma unroll
  for (int k = 0; k < 8; k++) o1[k] = tile[c + 8 + k][d];
  short* dst = Vt + (((size_t)(b * 16 + h) * 64) + d) * 2048 + t0 + c;
  *(short8*)dst       = o0;
  *(short8*)(dst + 8) = o1;
}

// ---------------------------------------------------------------------------
// GEMM 128x128, BK=32, 4 waves, double-buffered (for wide-N shapes with
// >=3 blocks/CU: qkv, ffn1).
// ---------------------------------------------------------------------------
template <bool GELU_, bool RESID, bool OUTBF16>
__global__ __launch_bounds__(256) void gemm_bt(
    const short* __restrict__ A, const short* __restrict__ Bt,
    const float* __restrict__ bias, const float* __restrict__ resid,
    void* __restrict__ Cout, int M, int N, int K)
{
  __shared__ __align__(16) short Abuf[2][128 * 32];
  __shared__ __align__(16) short Bbuf[2][128 * 32];
  const int tid = threadIdx.x, lane = tid & 63, wid = tid >> 6;
  const int wr = wid >> 1, wc = wid & 1;
  const int bm = blockIdx.x * 128, bn = blockIdx.y * 128;

  f32x4 acc[4][4] = {};

  const int arow  = wid * 32 + (lane >> 2);
  const int acol8 = (lane & 3) * 8;
  const short* Ag0 = A  + (size_t)(bm + arow)      * K + acol8;
  const short* Ag1 = A  + (size_t)(bm + arow + 16) * K + acol8;
  const short* Bg0 = Bt + (size_t)(bn + arow)      * K + acol8;
  const short* Bg1 = Bt + (size_t)(bn + arow + 16) * K + acol8;

  const int l0 = (wid * 32) * 32, l1 = (wid * 32 + 16) * 32;

  gl_lds16(Ag0, &Abuf[0][l0]);
  gl_lds16(Ag1, &Abuf[0][l1]);
  gl_lds16(Bg0, &Bbuf[0][l0]);
  gl_lds16(Bg1, &Bbuf[0][l1]);
  __syncthreads();

  int cur = 0;
  for (int k0 = 32; k0 < K; k0 += 32) {
    const int nxt = cur ^ 1;
    gl_lds16(Ag0 + k0, &Abuf[nxt][l0]);
    gl_lds16(Ag1 + k0, &Abuf[nxt][l1]);
    gl_lds16(Bg0 + k0, &Bbuf[nxt][l0]);
    gl_lds16(Bg1 + k0, &Bbuf[nxt][l1]);

    bf16x8 a[4], b[4];
#pragma unroll
    for (int mi = 0; mi < 4; mi++)
      a[mi] = *(const bf16x8*)&Abuf[cur][(wr * 64 + mi * 16 + (lane & 15)) * 32 + (lane >> 4) * 8];
#pragma unroll
    for (int ni = 0; ni < 4; ni++)
      b[ni] = *(const bf16x8*)&Bbuf[cur][(wc * 64 + ni * 16 + (lane & 15)) * 32 + (lane >> 4) * 8];
#pragma unroll
    for (int mi = 0; mi < 4; mi++)
#pragma unroll
      for (int ni = 0; ni < 4; ni++)
        acc[mi][ni] = mfma_bf16(a[mi], b[ni], acc[mi][ni]);

    __syncthreads();
    cur = nxt;
  }

  {
    bf16x8 a[4], b[4];
#pragma unroll
    for (int mi = 0; mi < 4; mi++)
      a[mi] = *(const bf16x8*)&Abuf[cur][(wr * 64 + mi * 16 + (lane & 15)) * 32 + (lane >> 4) * 8];
#pragma unroll
    for (int ni = 0; ni < 4; ni++)
      b[ni] = *(const bf16x8*)&Bbuf[cur][(wc * 64 + ni * 16 + (lane & 15)) * 32 + (lane >> 4) * 8];
#pragma unroll
    for (int mi = 0; mi < 4; mi++)
#pragma unroll
      for (int ni = 0; ni < 4; ni++)
        acc[mi][ni] = mfma_bf16(a[mi], b[ni], acc[mi][ni]);
  }

#pragma unroll
  for (int mi = 0; mi < 4; mi++) {
#pragma unroll
    for (int ni = 0; ni < 4; ni++) {
      const int col = bn + wc * 64 + ni * 16 + (lane & 15);
      const float bs = bias[col];
#pragma unroll
      for (int j = 0; j < 4; j++) {
        const int row = bm + wr * 64 + mi * 16 + (lane >> 4) * 4 + j;
        float v = acc[mi][ni][j] + bs;
        if (GELU_) v = 0.5f * v * (1.0f + erff(v * 0.70710678118654752f));
        if (RESID) v += resid[(size_t)row * N + col];
        if (OUTBF16) ((short*)Cout)[(size_t)row * N + col] = f2bf(v);
        else         ((float*)Cout)[(size_t)row * N + col] = v;
      }
    }
  }
}

// ---------------------------------------------------------------------------
// GEMM for narrow-N latency-bound shapes (o-proj, ffn2): 128x64 tile,
// 512 threads = 8 waves = 2 k-groups of 4 waves, cross-group LDS reduction.
// ---------------------------------------------------------------------------
template <bool GELU_, bool RESID, bool OUTBF16>
__global__ __launch_bounds__(512) void gemm_bt8(
    const short* __restrict__ A, const short* __restrict__ Bt,
    const float* __restrict__ bias, const float* __restrict__ resid,
    void* __restrict__ Cout, int M, int N, int K)
{
  __shared__ __align__(16) short Ab[2][2][128 * 32];   // [kg][buf] 32 KB
  __shared__ __align__(16) short Bb[2][2][64 * 32];    // [kg][buf] 16 KB
  const int tid = threadIdx.x, lane = tid & 63, wid = tid >> 6;
  const int kg = wid >> 2, w2 = wid & 3;
  const int wr = w2 >> 1, wc = w2 & 1;
  const int bm = blockIdx.x * 128, bn = blockIdx.y * 64;

  f32x4 acc[4][2] = {};

  const int r_l = lane >> 2;           // 0..15
  const int c8  = (lane & 3) * 8;
  const short* Ag0 = A  + (size_t)(bm + w2 * 32 + r_l)      * K + c8;
  const short* Ag1 = A  + (size_t)(bm + w2 * 32 + 16 + r_l) * K + c8;
  const short* Bg0 = Bt + (size_t)(bn + w2 * 16 + r_l)      * K + c8;

  const int la0 = (w2 * 32) * 32, la1 = (w2 * 32 + 16) * 32, lb0 = (w2 * 16) * 32;
  const int kbase = kg * 32;

  gl_lds16(Ag0 + kbase, &Ab[kg][0][la0]);
  gl_lds16(Ag1 + kbase, &Ab[kg][0][la1]);
  gl_lds16(Bg0 + kbase, &Bb[kg][0][lb0]);
  __syncthreads();

  const int nsteps = K >> 6;   // chunks per group
  int cur = 0;
  for (int i = 1; i < nsteps; ++i) {
    const int k0 = i * 64 + kbase;
    const int nxt = cur ^ 1;
    gl_lds16(Ag0 + k0, &Ab[kg][nxt][la0]);
    gl_lds16(Ag1 + k0, &Ab[kg][nxt][la1]);
    gl_lds16(Bg0 + k0, &Bb[kg][nxt][lb0]);

    bf16x8 a[4], b[2];
#pragma unroll
    for (int mi = 0; mi < 4; mi++)
      a[mi] = *(const bf16x8*)&Ab[kg][cur][(wr * 64 + mi * 16 + (lane & 15)) * 32 + (lane >> 4) * 8];
#pragma unroll
    for (int ni = 0; ni < 2; ni++)
      b[ni] = *(const bf16x8*)&Bb[kg][cur][(wc * 32 + ni * 16 + (lane & 15)) * 32 + (lane >> 4) * 8];
#pragma unroll
    for (int mi = 0; mi < 4; mi++)
#pragma unroll
      for (int ni = 0; ni < 2; ni++)
        acc[mi][ni] = mfma_bf16(a[mi], b[ni], acc[mi][ni]);

    __syncthreads();
    cur = nxt;
  }

  {
    bf16x8 a[4], b[2];
#pragma unroll
    for (int mi = 0; mi < 4; mi++)
      a[mi] = *(const bf16x8*)&Ab[kg][cur][(wr * 64 + mi * 16 + (lane & 15)) * 32 + (lane >> 4) * 8];
#pragma unroll
    for (int ni = 0; ni < 2; ni++)
      b[ni] = *(const bf16x8*)&Bb[kg][cur][(wc * 32 + ni * 16 + (lane & 15)) * 32 + (lane >> 4) * 8];
#pragma unroll
    for (int mi = 0; mi < 4; mi++)
#pragma unroll
      for (int ni = 0; ni < 2; ni++)
        acc[mi][ni] = mfma_bf16(a[mi], b[ni], acc[mi][ni]);
  }

  __syncthreads();

  float* red = (float*)&Ab[0][0][0];
  const int slot = (w2 * 64 + lane) * 8;
  if (kg == 1) {
#pragma unroll
    for (int mi = 0; mi < 4; mi++)
#pragma unroll
      for (int ni = 0; ni < 2; ni++)
        *(f32x4*)&red[(slot + mi * 2 + ni) * 4] = acc[mi][ni];
  }
  __syncthreads();
  if (kg == 0) {
#pragma unroll
    for (int mi = 0; mi < 4; mi++)
#pragma unroll
      for (int ni = 0; ni < 2; ni++)
        acc[mi][ni] += *(const f32x4*)&red[(slot + mi * 2 + ni) * 4];

#pragma unroll
    for (int mi = 0; mi < 4; mi++) {
#pragma unroll
      for (int ni = 0; ni < 2; ni++) {
        const int col = bn + wc * 32 + ni * 16 + (lane & 15);
        const float bs = bias[col];
#pragma unroll
        for (int j = 0; j < 4; j++) {
          const int row = bm + wr * 64 + mi * 16 + (lane >> 4) * 4 + j;
          float v = acc[mi][ni][j] + bs;
          if (GELU_) v = 0.5f * v * (1.0f + erff(v * 0.70710678118654752f));
          if (RESID) v += resid[(size_t)row * N + col];
          if (OUTBF16) ((short*)Cout)[(size_t)row * N + col] = f2bf(v);
          else         ((float*)Cout)[(size_t)row * N + col] = v;
        }
      }
    }
  }
}

// ---------------------------------------------------------------------------
// Flash attention, swapped-QK^T, KVBLK=128, defer-max, in-register P.
// K-LDS row r holds key kt + a(r) where a(r)=32(kc&3)+8g_r+4(kc>>2)+j_r
// (bijection on [0,128)), chosen so each lane's post-softmax P values,
// packed with v_cvt_pk_bf16_f32, form the PV A-fragments directly.
// V staged linearly (its k-slot space matches PV's). No P LDS at all.
// LDS = 32 KB -> 5 blocks/CU LDS-limit; grid is 4 blocks/CU -> co-resident.
// ---------------------------------------------------------------------------
__global__ __launch_bounds__(256) void attn_k(
    const short* __restrict__ Qg, const short* __restrict__ Kg,
    const short* __restrict__ Vt, short* __restrict__ Og)
{
  const int b = blockIdx.z, h = blockIdx.y, q0 = blockIdx.x * 64;
  const int tid = threadIdx.x, lane = tid & 63, w = tid >> 6;
  const int qlane = lane & 15, g = lane >> 4;

  __shared__ __align__(16) short Kl[128 * 64];      // 16 KB
  __shared__ __align__(16) short Vl[64 * 128];      // 16 KB

  char* KbC = (char*)Kl;
  char* VbC = (char*)Vl;

  const size_t qrow = (size_t)(b * SEQ + q0 + w * 16 + qlane) * LDQKV + h * 64;
  const bf16x8 qf0 = *(const bf16x8*)&Qg[qrow + g * 8];
  const bf16x8 qf1 = *(const bf16x8*)&Qg[qrow + 32 + g * 8];

  // K staging with key permutation a(r); global SOURCE is per-lane so the
  // permutation costs nothing (4 precomputed base pointers).
  const int kslot = (lane & 7) ^ ((lane >> 3) & 7);
  const short* Kg_a[4];
#pragma unroll
  for (int i = 0; i < 4; i++) {
    const int r  = i * 32 + w * 8 + (lane >> 3);
    const int kc = r >> 4, gr = (r >> 2) & 3, jr = r & 3;
    const int a  = 32 * (kc & 3) + 8 * gr + 4 * (kc >> 2) + jr;
    Kg_a[i] = Kg + ((size_t)(b * SEQ) + a) * LDQKV + h * 64 + kslot * 8;
  }
  const short* Vt_head = Vt + ((size_t)(b * 16 + h) * 64) * 2048;

  float m_run = -1e30f, l_run = 0.f;
  f32x4 oacc[4] = {};
  const float C = 0.125f * 1.44269504088896f;   // head-scale * log2(e)

  for (int kt = 0; kt < SEQ; kt += 128) {
    // ---- stage K (permuted rows) and V^T (linear)
#pragma unroll
    for (int i = 0; i < 4; i++)
      gl_lds16(Kg_a[i] + (size_t)kt * LDQKV, &Kl[(i * 32 + w * 8) * 64]);
#pragma unroll
    for (int i = 0; i < 4; i++) {
      const int dloc = i * 4 + (lane >> 4);
      const int vs = (lane & 15) ^ dloc;
      gl_lds16(Vt_head + (size_t)(w * 16 + dloc) * 2048 + kt + vs * 8,
               &Vl[(w * 16 + i * 4) * 128]);
    }
    __syncthreads();

    // ---- S^T = mfma(K, Q): s[kc][j] = S[q=qlane][LDS key-row 16kc+4g+j]
    f32x4 s[8];
#pragma unroll
    for (int kc = 0; kc < 8; kc++) {
      const int kr = kc * 16 + qlane;
      const char* kp = KbC + kr * 128;
      const int sw = (kr & 7) << 4;
      bf16x8 kf0 = *(const bf16x8*)(kp + ((g * 16) ^ sw));
      bf16x8 kf1 = *(const bf16x8*)(kp + ((64 + g * 16) ^ sw));
      f32x4 z = {};
      z = mfma_bf16(kf0, qf0, z);
      z = mfma_bf16(kf1, qf1, z);
      s[kc] = z;
    }

    // ---- tile max (in-lane tree + 2 shfl)
    f32x4 m4 = s[0];
#pragma unroll
    for (int kc = 1; kc < 8; kc++) {
      m4[0] = fmaxf(m4[0], s[kc][0]); m4[1] = fmaxf(m4[1], s[kc][1]);
      m4[2] = fmaxf(m4[2], s[kc][2]); m4[3] = fmaxf(m4[3], s[kc][3]);
    }
    float mt = fmaxf(fmaxf(m4[0], m4[1]), fmaxf(m4[2], m4[3]));
    mt = fmaxf(mt, __shfl_xor(mt, 16));
    mt = fmaxf(mt, __shfl_xor(mt, 32));

    // ---- defer-max rescale
    if (!__all(mt - m_run <= 40.0f)) {
      const float mnew = fmaxf(m_run, mt);
      const float r = exp2f((m_run - mnew) * C);
      m_run = mnew;
      l_run *= r;
#pragma unroll
      for (int j = 0; j < 4; j++) {
        const float rj = __shfl(r, g * 4 + j);
#pragma unroll
        for (int dt = 0; dt < 4; dt++) oacc[dt][j] *= rj;
      }
    }

    // ---- P = exp2(s*C - m*C), row-sum, pack into PV A-fragment words:
    // s[kc][j] is key 32(kc&3)+8g+4(kc>>2)+j  ->  pw[kc&3][2(kc>>2)+(j>>1)]
    const float nmc = -m_run * C;
    float rs = 0.f;
    unsigned pw[4][4];
#pragma unroll
    for (int kc = 0; kc < 8; kc++) {
      f32x4 p;
#pragma unroll
      for (int j = 0; j < 4; j++) p[j] = exp2f(fmaf(s[kc][j], C, nmc));
      rs += (p[0] + p[1]) + (p[2] + p[3]);
      unsigned w0, w1;
      asm("v_cvt_pk_bf16_f32 %0, %1, %2" : "=v"(w0) : "v"(p[0]), "v"(p[1]));
      asm("v_cvt_pk_bf16_f32 %0, %1, %2" : "=v"(w1) : "v"(p[2]), "v"(p[3]));
      pw[kc & 3][2 * (kc >> 2) + 0] = w0;
      pw[kc & 3][2 * (kc >> 2) + 1] = w1;
    }
    rs += __shfl_xor(rs, 16);
    rs += __shfl_xor(rs, 32);
    l_run += rs;

    // ---- PV: O[q][d] += P[q][k] * Vt[d][k]; pf comes straight from pw
#pragma unroll
    for (int ks = 0; ks < 4; ks++) {
      union { unsigned u[4]; bf16x8 v; } pf;
      pf.u[0] = pw[ks][0]; pf.u[1] = pw[ks][1];
      pf.u[2] = pw[ks][2]; pf.u[3] = pw[ks][3];
#pragma unroll
      for (int dt = 0; dt < 4; dt++) {
        const int vr = dt * 16 + qlane;
        bf16x8 vf = *(const bf16x8*)(VbC + vr * 256 + ((64 * ks + 16 * g) ^ ((vr & 15) << 4)));
        oacc[dt] = mfma_bf16(pf.v, vf, oacc[dt]);
      }
    }
    __syncthreads();
  }

  // ---- epilogue
  const float linv = 1.f / l_run;
#pragma unroll
  for (int j = 0; j < 4; j++) {
    const float lj = __shfl(linv, g * 4 + j);
    const int tok = q0 + w * 16 + g * 4 + j;
#pragma unroll
    for (int dt = 0; dt < 4; dt++)
      Og[(size_t)(b * SEQ + tok) * DM + h * 64 + dt * 16 + qlane] = f2bf(oacc[dt][j] * lj);
  }
}

// ---------------------------------------------------------------------------
extern "C" void kernel_launch(void* const* d_in, const int* in_sizes, int n_in,
                              void* d_out, int out_size, void* d_ws, size_t ws_size,
                              hipStream_t stream)
{
  const float* x    = (const float*)d_in[0];
  const float* Wq   = (const float*)d_in[1];
  const float* bq   = (const float*)d_in[2];
  const float* Wk   = (const float*)d_in[3];
  const float* bk   = (const float*)d_in[4];
  const float* Wv   = (const float*)d_in[5];
  const float* bv   = (const float*)d_in[6];
  const float* Wo   = (const float*)d_in[7];
  const float* bo   = (const float*)d_in[8];
  const float* W1   = (const float*)d_in[9];
  const float* b1   = (const float*)d_in[10];
  const float* W2   = (const float*)d_in[11];
  const float* b2   = (const float*)d_in[12];
  const float* ln1g = (const float*)d_in[13];
  const float* ln1b = (const float*)d_in[14];
  const float* ln2g = (const float*)d_in[15];
  const float* ln2b = (const float*)d_in[16];

  char* ws = (char*)d_ws;
  const size_t MB = 1024 * 1024;
  short* Wqkvt = (short*)(ws + 0 * MB);           // [3072][1024] bf16
  short* Wqt   = Wqkvt;
  short* Wkt   = (short*)(ws + 2 * MB);
  short* Wvt   = (short*)(ws + 4 * MB);
  short* Wot   = (short*)(ws + 6 * MB);           // [1024][1024]
  short* W1t   = (short*)(ws + 8 * MB);           // [4096][1024]
  short* W2t   = (short*)(ws + 16 * MB);          // [1024][4096]
  short* hbuf  = (short*)(ws + 24 * MB);          // [4096][1024] bf16
  short* QKV   = (short*)(ws + 32 * MB);          // [4096][3072] bf16
  short* AO    = (short*)(ws + 56 * MB);          // [4096][1024] bf16
  float* x1    = (float*)(ws + 64 * MB);          // [4096][1024] fp32 (after attn)
  short* Vtb   = (short*)(ws + 64 * MB);          // [2048][2048] bf16 Vt, dead before x1 written
  float* bqkv  = (float*)(ws + 80 * MB);          // [3072] fp32
  short* gbuf  = (short*)(ws + 32 * MB);          // [4096][4096] bf16, aliases QKV+AO

  dim3 tb(256);

  transpose_cast_k<<<dim3(32, 32),  tb, 0, stream>>>(Wq, Wqt, 1024, 1024);
  transpose_cast_k<<<dim3(32, 32),  tb, 0, stream>>>(Wk, Wkt, 1024, 1024);
  transpose_cast_k<<<dim3(32, 32),  tb, 0, stream>>>(Wv, Wvt, 1024, 1024);
  transpose_cast_k<<<dim3(32, 32),  tb, 0, stream>>>(Wo, Wot, 1024, 1024);
  transpose_cast_k<<<dim3(128, 32), tb, 0, stream>>>(W1, W1t, 1024, 4096);
  transpose_cast_k<<<dim3(32, 128), tb, 0, stream>>>(W2, W2t, 4096, 1024);
  concat_bias_k<<<dim3(12), tb, 0, stream>>>(bq, bk, bv, bqkv);

  // LN1
  ln_k<<<dim3(MTOK), tb, 0, stream>>>(x, ln1g, ln1b, hbuf);

  // fused QKV projection: [4096,1024] x [3072,1024]^T -> [4096,3072] bf16
  gemm_bt<false, false, true><<<dim3(32, 24), tb, 0, stream>>>(
      hbuf, Wqkvt, bqkv, nullptr, QKV, MTOK, 3072, 1024);

  // V transpose -> Vt [(b*16+h)*64+d][2048]
  vtrans_k<<<dim3(32, 16, 2), tb, 0, stream>>>(QKV + 2048, Vtb);

  // attention
  attn_k<<<dim3(32, 16, 2), tb, 0, stream>>>(QKV, QKV + 1024, Vtb, AO);

  // O-projection + residual: x1 = x + AO @ Wo + bo  (fp32 out)  [8-wave k-split]
  gemm_bt8<false, true, false><<<dim3(32, 16), dim3(512), 0, stream>>>(
      AO, Wot, bo, x, x1, MTOK, 1024, 1024);

  // LN2
  ln_k<<<dim3(MTOK), tb, 0, stream>>>(x1, ln2g, ln2b, hbuf);

  // FFN1 + GELU: [4096,1024] x [4096,1024]^T -> [4096,4096] bf16
  gemm_bt<true, false, true><<<dim3(32, 32), tb, 0, stream>>>(
      hbuf, W1t, b1, nullptr, gbuf, MTOK, 4096, 1024);

  // FFN2 + residual -> d_out fp32  [8-wave k-split]
  gemm_bt8<false, true, false><<<dim3(32, 16), dim3(512), 0, stream>>>(
      gbuf, W2t, b2, x1, (float*)d_out, MTOK, 1024, 4096);
}